// Round 1
// baseline (2060.760 us; speedup 1.0000x reference)
//
#include <hip/hip_runtime.h>
#include <hip/hip_bf16.h>
#include <math.h>

#define NN 20000
#define EE 320000
// dims
#define HID 64
#define EHID 32
#define HEADS 4

// ---------------------------------------------------------------------------
// Node encoder: Linear(9,32)+ReLU+Linear(32,64)+LayerNorm(64). Thread per node.
__global__ __launch_bounds__(256) void k_node_enc(
    const float* __restrict__ x, const float* __restrict__ w1, const float* __restrict__ b1,
    const float* __restrict__ w2, const float* __restrict__ b2,
    const float* __restrict__ g, const float* __restrict__ beta,
    float* __restrict__ h) {
  int n = blockIdx.x * blockDim.x + threadIdx.x;
  if (n >= NN) return;
  float xin[9];
#pragma unroll
  for (int k = 0; k < 9; k++) xin[k] = x[n * 9 + k];
  float hid[32];
#pragma unroll
  for (int j = 0; j < 32; j++) {
    float a = b1[j];
#pragma unroll
    for (int k = 0; k < 9; k++) a += xin[k] * w1[k * 32 + j];
    hid[j] = fmaxf(a, 0.f);
  }
  float o[64];
  float s = 0.f;
  for (int j = 0; j < 64; j++) {
    float a = b2[j];
#pragma unroll
    for (int k = 0; k < 32; k++) a += hid[k] * w2[k * 64 + j];
    o[j] = a;
    s += a;
  }
  float m = s * (1.f / 64.f);
  float v = 0.f;
  for (int j = 0; j < 64; j++) { float d = o[j] - m; v += d * d; }
  v *= (1.f / 64.f);
  float inv = rsqrtf(v + 1e-5f);
  for (int j = 0; j < 64; j++) h[n * 64 + j] = (o[j] - m) * inv * g[j] + beta[j];
}

// ---------------------------------------------------------------------------
// Edge encoder: Linear(4,16)+ReLU+Linear(16,32)+LayerNorm(32). Thread per edge.
__global__ __launch_bounds__(256) void k_edge_enc(
    const float* __restrict__ ea, const float* __restrict__ w1, const float* __restrict__ b1,
    const float* __restrict__ w2, const float* __restrict__ b2,
    const float* __restrict__ g, const float* __restrict__ beta,
    float* __restrict__ ef) {
  int e = blockIdx.x * blockDim.x + threadIdx.x;
  if (e >= EE) return;
  float xin[4];
#pragma unroll
  for (int k = 0; k < 4; k++) xin[k] = ea[e * 4 + k];
  float hid[16];
#pragma unroll
  for (int j = 0; j < 16; j++) {
    float a = b1[j];
#pragma unroll
    for (int k = 0; k < 4; k++) a += xin[k] * w1[k * 16 + j];
    hid[j] = fmaxf(a, 0.f);
  }
  float o[32];
  float s = 0.f;
#pragma unroll
  for (int j = 0; j < 32; j++) {
    float a = b2[j];
#pragma unroll
    for (int k = 0; k < 16; k++) a += hid[k] * w2[k * 32 + j];
    o[j] = a;
    s += a;
  }
  float m = s * (1.f / 32.f);
  float v = 0.f;
#pragma unroll
  for (int j = 0; j < 32; j++) { float d = o[j] - m; v += d * d; }
  v *= (1.f / 32.f);
  float inv = rsqrtf(v + 1e-5f);
#pragma unroll
  for (int j = 0; j < 32; j++) ef[e * 32 + j] = (o[j] - m) * inv * g[j] + beta[j];
}

// ---------------------------------------------------------------------------
// Risk MLP: sigmoid(tanh([h[row], ef] @ w1 + b1) @ w2 + b2). One wave per edge,
// 4 edges sequentially per wave (16 per block) to amortize weight fetch (L1).
__global__ __launch_bounds__(256) void k_risk(
    const float* __restrict__ h, const float* __restrict__ ef, const int* __restrict__ ei,
    const float* __restrict__ w1, const float* __restrict__ b1,
    const float* __restrict__ w2, const float* __restrict__ b2_,
    float* __restrict__ rw) {
  __shared__ float ins[4][96];
  int t = threadIdx.x, wv = t >> 6, lane = t & 63;
  int e0 = blockIdx.x * 16 + wv * 4;
  float bb1 = b1[lane];
  float ww2 = w2[lane];
  for (int q = 0; q < 4; q++) {
    int e = e0 + q;
    if (e < EE) {
      int r = ei[e];  // row
      ins[wv][lane] = h[r * 64 + lane];
      if (lane < 32) ins[wv][64 + lane] = ef[e * 32 + lane];
    }
    __syncthreads();
    if (e < EE) {
      float a = bb1;
      for (int k = 0; k < 96; k++) a += ins[wv][k] * w1[k * 64 + lane];
      float v = tanhf(a) * ww2;
      for (int off = 32; off; off >>= 1) v += __shfl_xor(v, off);
      if (lane == 0) rw[e] = 1.f / (1.f + expf(-(v + b2_[0])));
    }
    __syncthreads();
  }
}

// ---------------------------------------------------------------------------
// xproj = xh @ wl  -> [N, 256]. 16 nodes per block for weight reuse.
#define XPN 16
__global__ __launch_bounds__(256) void k_xproj(
    const float* __restrict__ xh, const float* __restrict__ wl,
    float* __restrict__ xproj) {
  __shared__ float xs[XPN][64];
  int t = threadIdx.x;
  int n0 = blockIdx.x * XPN;
  for (int i = t; i < XPN * 64; i += 256) {
    int m = i >> 6, k = i & 63;
    int n = n0 + m;
    xs[m][k] = (n < NN) ? xh[n * 64 + k] : 0.f;
  }
  __syncthreads();
  float acc[XPN];
#pragma unroll
  for (int m = 0; m < XPN; m++) acc[m] = 0.f;
  for (int k = 0; k < 64; k++) {
    float wv = wl[k * 256 + t];
#pragma unroll
    for (int m = 0; m < XPN; m++) acc[m] += xs[m][k] * wv;
  }
#pragma unroll
  for (int m = 0; m < XPN; m++) {
    int n = n0 + m;
    if (n < NN) xproj[n * 256 + t] = acc[m];
  }
}

// ---------------------------------------------------------------------------
// per-(node,head) attention dots: di = xproj[n,h]·wa_i, dj = xproj[n,h]·wa_j
__global__ __launch_bounds__(256) void k_didj(
    const float* __restrict__ xproj, const float* __restrict__ wa,
    float* __restrict__ di, float* __restrict__ dj) {
  int t = threadIdx.x, lane = t & 63, wv = t >> 6;
  int idx = blockIdx.x * 4 + wv;  // over N*HEADS
  if (idx >= NN * 4) return;
  int n = idx >> 2, head = idx & 3;
  float xv = xproj[n * 256 + head * 64 + lane];
  float vi = xv * wa[lane];
  float vj = xv * wa[64 + lane];
  for (int off = 32; off; off >>= 1) { vi += __shfl_xor(vi, off); vj += __shfl_xor(vj, off); }
  if (lane == 0) { di[idx] = vi; dj[idx] = vj; }
}

// ---------------------------------------------------------------------------
// alpha_raw per edge per head + block max partials (for global softmax).
__global__ __launch_bounds__(256) void k_alpha(
    const float* __restrict__ ef, const int* __restrict__ ei,
    const float* __restrict__ di, const float* __restrict__ dj,
    const float* __restrict__ rw, const float* __restrict__ wa_e,
    float* __restrict__ araw, float* __restrict__ maxpart, int nb) {
  __shared__ float red[256];
  int t = threadIdx.x;
  int e = blockIdx.x * 256 + t;
  float mh[4] = {-1e30f, -1e30f, -1e30f, -1e30f};
  if (e < EE) {
    float dev = 0.f;
#pragma unroll
    for (int c = 0; c < 32; c++) dev += ef[e * 32 + c] * wa_e[c];
    int r = ei[e], cl = ei[EE + e];
    float rv = rw[e];
#pragma unroll
    for (int h = 0; h < 4; h++) {
      float z = di[r * 4 + h] + dj[cl * 4 + h] + dev;
      z = (z >= 0.f) ? z : 0.2f * z;  // leaky_relu(0.2)
      z *= rv;
      araw[e * 4 + h] = z;
      mh[h] = z;
    }
  }
  for (int h = 0; h < 4; h++) {
    red[t] = mh[h];
    __syncthreads();
    for (int s = 128; s; s >>= 1) { if (t < s) red[t] = fmaxf(red[t], red[t + s]); __syncthreads(); }
    if (t == 0) maxpart[h * nb + blockIdx.x] = red[0];
    __syncthreads();
  }
}

__global__ __launch_bounds__(256) void k_redmax(
    const float* __restrict__ maxpart, float* __restrict__ gmax, int nb) {
  __shared__ float red[256];
  int t = threadIdx.x;
  for (int h = 0; h < 4; h++) {
    float m = -1e30f;
    for (int i = t; i < nb; i += 256) m = fmaxf(m, maxpart[h * nb + i]);
    red[t] = m;
    __syncthreads();
    for (int s = 128; s; s >>= 1) { if (t < s) red[t] = fmaxf(red[t], red[t + s]); __syncthreads(); }
    if (t == 0) gmax[h] = red[0];
    __syncthreads();
  }
}

__global__ __launch_bounds__(256) void k_exp(
    const float* __restrict__ araw, const float* __restrict__ gmax,
    float* __restrict__ p, float* __restrict__ sumpart, int nb) {
  __shared__ float red[256];
  int t = threadIdx.x;
  int e = blockIdx.x * 256 + t;
  float sh[4] = {0.f, 0.f, 0.f, 0.f};
  if (e < EE) {
#pragma unroll
    for (int h = 0; h < 4; h++) {
      float pv = expf(araw[e * 4 + h] - gmax[h]);
      p[e * 4 + h] = pv;
      sh[h] = pv;
    }
  }
  for (int h = 0; h < 4; h++) {
    red[t] = sh[h];
    __syncthreads();
    for (int s = 128; s; s >>= 1) { if (t < s) red[t] += red[t + s]; __syncthreads(); }
    if (t == 0) sumpart[h * nb + blockIdx.x] = red[0];
    __syncthreads();
  }
}

__global__ __launch_bounds__(256) void k_redsum(
    const float* __restrict__ sumpart, float* __restrict__ invsum, int nb) {
  __shared__ float red[256];
  int t = threadIdx.x;
  for (int h = 0; h < 4; h++) {
    float s = 0.f;
    for (int i = t; i < nb; i += 256) s += sumpart[h * nb + i];
    red[t] = s;
    __syncthreads();
    for (int st = 128; st; st >>= 1) { if (t < st) red[t] += red[t + st]; __syncthreads(); }
    if (t == 0) invsum[h] = 1.f / red[0];
    __syncthreads();
  }
}

// ---------------------------------------------------------------------------
// CSR build over col (reused for all 3 layers)
__global__ __launch_bounds__(256) void k_zero(int* __restrict__ counts) {
  int i = blockIdx.x * 256 + threadIdx.x;
  if (i < NN) counts[i] = 0;
}
__global__ __launch_bounds__(256) void k_hist(const int* __restrict__ ei, int* __restrict__ counts) {
  int e = blockIdx.x * 256 + threadIdx.x;
  if (e < EE) atomicAdd(&counts[ei[EE + e]], 1);
}
__global__ __launch_bounds__(1024) void k_scan(
    const int* __restrict__ counts, int* __restrict__ rowptr, int* __restrict__ cursor) {
  __shared__ int tmp[1024];
  __shared__ int base_s;
  int t = threadIdx.x;
  if (t == 0) base_s = 0;
  __syncthreads();
  for (int start = 0; start < NN; start += 1024) {
    int idx = start + t;
    int c = (idx < NN) ? counts[idx] : 0;
    int v = c;
    tmp[t] = v;
    __syncthreads();
    for (int off = 1; off < 1024; off <<= 1) {
      int add = (t >= off) ? tmp[t - off] : 0;
      __syncthreads();
      v += add;
      tmp[t] = v;
      __syncthreads();
    }
    int base = base_s;
    if (idx < NN) { rowptr[idx] = base + v - c; cursor[idx] = base + v - c; }
    __syncthreads();
    if (t == 1023) base_s = base + v;
    __syncthreads();
  }
  if (t == 0) rowptr[NN] = base_s;
}
__global__ __launch_bounds__(256) void k_fill(
    const int* __restrict__ ei, int* __restrict__ cursor, int* __restrict__ csr) {
  int e = blockIdx.x * 256 + threadIdx.x;
  if (e < EE) {
    int pos = atomicAdd(&cursor[ei[EE + e]], 1);
    csr[pos] = e;
  }
}

// ---------------------------------------------------------------------------
// Aggregation: for node n, s[h] = Σ p[e,h], t[h][c] = Σ p[e,h]*ef[e,c] over
// incoming edges (col==n). One wave per node; lane = (h-pair, channel).
__global__ __launch_bounds__(256) void k_agg(
    const float* __restrict__ p, const float* __restrict__ ef,
    const int* __restrict__ rowptr, const int* __restrict__ csr,
    const float* __restrict__ invsum,
    float* __restrict__ sagg, float* __restrict__ tagg) {
  int t = threadIdx.x, wv = t >> 6, lane = t & 63;
  int n = blockIdx.x * 4 + wv;
  if (n >= NN) return;
  int c = lane & 31, hp = lane >> 5;
  int h0 = hp * 2, h1 = h0 + 1;
  float a0 = 0.f, a1 = 0.f, s0 = 0.f, s1 = 0.f;
  int beg = rowptr[n], end = rowptr[n + 1];
  for (int i = beg; i < end; i++) {
    int e = csr[i];
    float p0 = p[e * 4 + h0];
    float p1 = p[e * 4 + h1];
    float ev = ef[e * 32 + c];
    a0 += p0 * ev;
    a1 += p1 * ev;
    s0 += p0;
    s1 += p1;
  }
  float i0 = invsum[h0], i1 = invsum[h1];
  tagg[n * 128 + h0 * 32 + c] = a0 * i0;
  tagg[n * 128 + h1 * 32 + c] = a1 * i1;
  if (c == 0) { sagg[n * 4 + h0] = s0 * i0; sagg[n * 4 + h1] = s1 * i1; }
}

// ---------------------------------------------------------------------------
// Node update: u = 0.25*(Σ_h xproj[n,h]*s[h] + Σ_h t[h]@we_h); xh = relu(u@wo+wob)
#define UPN 16
__global__ __launch_bounds__(256) void k_update(
    const float* __restrict__ xproj, const float* __restrict__ sagg,
    const float* __restrict__ tagg, const float* __restrict__ we,
    const float* __restrict__ wo, const float* __restrict__ wob,
    float* __restrict__ xh_out) {
  __shared__ float ts[UPN][128];
  __shared__ float ss[UPN][4];
  __shared__ float us[UPN][64];
  int t = threadIdx.x;
  int n0 = blockIdx.x * UPN;
  for (int i = t; i < UPN * 128; i += 256) {
    int m = i >> 7, k = i & 127;
    int n = n0 + m;
    ts[m][k] = (n < NN) ? tagg[n * 128 + k] : 0.f;
  }
  for (int i = t; i < UPN * 4; i += 256) {
    int m = i >> 2, hh = i & 3;
    int n = n0 + m;
    ss[m][hh] = (n < NN) ? sagg[n * 4 + hh] : 0.f;
  }
  __syncthreads();
  int j = t & 63, grp = t >> 6;  // 4 groups x 4 nodes each
  float u[4];
#pragma unroll
  for (int q = 0; q < 4; q++) {
    int m = grp * 4 + q;
    int n = n0 + m;
    float uu = 0.f;
#pragma unroll
    for (int h = 0; h < 4; h++)
      uu += ((n < NN) ? xproj[n * 256 + h * 64 + j] : 0.f) * ss[m][h];
    u[q] = uu;
  }
  for (int h = 0; h < 4; h++) {
    for (int c = 0; c < 32; c++) {
      float wv = we[c * 256 + h * 64 + j];
#pragma unroll
      for (int q = 0; q < 4; q++) u[q] += ts[grp * 4 + q][h * 32 + c] * wv;
    }
  }
#pragma unroll
  for (int q = 0; q < 4; q++) us[grp * 4 + q][j] = 0.25f * u[q];
  __syncthreads();
  float o[4];
#pragma unroll
  for (int q = 0; q < 4; q++) o[q] = wob[j];
  for (int k = 0; k < 64; k++) {
    float wv = wo[k * 64 + j];
#pragma unroll
    for (int q = 0; q < 4; q++) o[q] += us[grp * 4 + q][k] * wv;
  }
#pragma unroll
  for (int q = 0; q < 4; q++) {
    int n = n0 + grp * 4 + q;
    if (n < NN) xh_out[n * 64 + j] = fmaxf(o[q], 0.f);
  }
}

// ---------------------------------------------------------------------------
// Output layer: Linear(64,128)+ReLU+Linear(128,256)+LayerNorm(256). 4 nodes/block.
#define OPN 4
__global__ __launch_bounds__(256) void k_out(
    const float* __restrict__ xh, const float* __restrict__ w1, const float* __restrict__ b1,
    const float* __restrict__ w2, const float* __restrict__ b2,
    const float* __restrict__ g, const float* __restrict__ beta,
    float* __restrict__ out) {
  __shared__ float xs[OPN][64];
  __shared__ float hs[OPN][128];
  __shared__ float red[256];
  int t = threadIdx.x;
  int n0 = blockIdx.x * OPN;
  for (int i = t; i < OPN * 64; i += 256) {
    int m = i >> 6, k = i & 63;
    int n = n0 + m;
    xs[m][k] = (n < NN) ? xh[n * 64 + k] : 0.f;
  }
  __syncthreads();
  for (int i = t; i < OPN * 128; i += 256) {
    int m = i >> 7, jj = i & 127;
    float a = b1[jj];
#pragma unroll
    for (int k = 0; k < 64; k++) a += xs[m][k] * w1[k * 128 + jj];
    hs[m][jj] = fmaxf(a, 0.f);
  }
  __syncthreads();
  float o[OPN];
#pragma unroll
  for (int m = 0; m < OPN; m++) o[m] = b2[t];
  for (int k = 0; k < 128; k++) {
    float wv = w2[k * 256 + t];
#pragma unroll
    for (int m = 0; m < OPN; m++) o[m] += hs[m][k] * wv;
  }
  for (int m = 0; m < OPN; m++) {
    red[t] = o[m];
    __syncthreads();
    for (int s = 128; s; s >>= 1) { if (t < s) red[t] += red[t + s]; __syncthreads(); }
    float mean = red[0] * (1.f / 256.f);
    __syncthreads();
    float d = o[m] - mean;
    red[t] = d * d;
    __syncthreads();
    for (int s = 128; s; s >>= 1) { if (t < s) red[t] += red[t + s]; __syncthreads(); }
    float var = red[0] * (1.f / 256.f);
    __syncthreads();
    int n = n0 + m;
    if (n < NN) out[n * 256 + t] = d * rsqrtf(var + 1e-5f) * g[t] + beta[t];
  }
}

// ---------------------------------------------------------------------------
extern "C" void kernel_launch(void* const* d_in, const int* in_sizes, int n_in,
                              void* d_out, int out_size, void* d_ws, size_t ws_size,
                              hipStream_t stream) {
  const float* x         = (const float*)d_in[0];
  const float* edge_attr = (const float*)d_in[1];
  const int*   ei        = (const int*)d_in[2];
  const float* ne_w1 = (const float*)d_in[3];
  const float* ne_b1 = (const float*)d_in[4];
  const float* ne_w2 = (const float*)d_in[5];
  const float* ne_b2 = (const float*)d_in[6];
  const float* ne_g  = (const float*)d_in[7];
  const float* ne_be = (const float*)d_in[8];
  const float* ee_w1 = (const float*)d_in[9];
  const float* ee_b1 = (const float*)d_in[10];
  const float* ee_w2 = (const float*)d_in[11];
  const float* ee_b2 = (const float*)d_in[12];
  const float* ee_g  = (const float*)d_in[13];
  const float* ee_be = (const float*)d_in[14];
  const float* ra_w1 = (const float*)d_in[15];
  const float* ra_b1 = (const float*)d_in[16];
  const float* ra_w2 = (const float*)d_in[17];
  const float* ra_b2 = (const float*)d_in[18];
  const float* gat_wl  = (const float*)d_in[19];
  const float* gat_wa  = (const float*)d_in[20];
  const float* gat_we  = (const float*)d_in[21];
  const float* gat_wo  = (const float*)d_in[22];
  const float* gat_wob = (const float*)d_in[23];
  const float* ow_1 = (const float*)d_in[24];
  const float* ob_1 = (const float*)d_in[25];
  const float* ow_2 = (const float*)d_in[26];
  const float* ob_2 = (const float*)d_in[27];
  const float* o_g  = (const float*)d_in[28];
  const float* o_be = (const float*)d_in[29];
  float* out = (float*)d_out;

  char* wsb = (char*)d_ws;
  size_t off = 0;
  auto af = [&](size_t elems) -> float* { float* p = (float*)(wsb + off); off += elems * sizeof(float); return p; };
  auto ai = [&](size_t elems) -> int*   { int*   p = (int*)(wsb + off);   off += elems * sizeof(int);   return p; };

  const int nb = EE / 256;  // 1250

  float* h      = af((size_t)NN * 64);
  float* xh2    = af((size_t)NN * 64);
  float* ef     = af((size_t)EE * 32);
  float* rw     = af((size_t)EE);
  float* xproj  = af((size_t)NN * 256);
  float* di     = af((size_t)NN * 4);
  float* dj     = af((size_t)NN * 4);
  float* araw   = af((size_t)EE * 4);
  float* p      = af((size_t)EE * 4);
  float* sagg   = af((size_t)NN * 4);
  float* tagg   = af((size_t)NN * 128);
  float* maxpart= af((size_t)4 * nb);
  float* sumpart= af((size_t)4 * nb);
  float* gmax   = af(4);
  float* invsum = af(4);
  int* counts = ai(NN);
  int* rowptr = ai(NN + 1);
  int* cursor = ai(NN);
  int* csr    = ai(EE);
  (void)ws_size; (void)n_in; (void)in_sizes; (void)out_size;

  // encoders
  k_node_enc<<<(NN + 255) / 256, 256, 0, stream>>>(x, ne_w1, ne_b1, ne_w2, ne_b2, ne_g, ne_be, h);
  k_edge_enc<<<EE / 256, 256, 0, stream>>>(edge_attr, ee_w1, ee_b1, ee_w2, ee_b2, ee_g, ee_be, ef);
  // risk weights
  k_risk<<<EE / 16, 256, 0, stream>>>(h, ef, ei, ra_w1, ra_b1, ra_w2, ra_b2, rw);
  // CSR over col
  k_zero<<<(NN + 255) / 256, 256, 0, stream>>>(counts);
  k_hist<<<EE / 256, 256, 0, stream>>>(ei, counts);
  k_scan<<<1, 1024, 0, stream>>>(counts, rowptr, cursor);
  k_fill<<<EE / 256, 256, 0, stream>>>(ei, cursor, csr);

  const float* xh_cur = h;
  float* bufs[2] = {xh2, h};
  for (int l = 0; l < 3; l++) {
    const float* wl  = gat_wl + (size_t)l * 64 * 256;
    const float* wa  = gat_wa + (size_t)l * 160;
    const float* we  = gat_we + (size_t)l * 32 * 256;
    const float* wo  = gat_wo + (size_t)l * 64 * 64;
    const float* wob = gat_wob + (size_t)l * 64;
    float* xh_next = bufs[l & 1];

    k_xproj<<<(NN + XPN - 1) / XPN, 256, 0, stream>>>(xh_cur, wl, xproj);
    k_didj<<<NN, 256, 0, stream>>>(xproj, wa, di, dj);
    k_alpha<<<nb, 256, 0, stream>>>(ef, ei, di, dj, rw, wa + 128, araw, maxpart, nb);
    k_redmax<<<1, 256, 0, stream>>>(maxpart, gmax, nb);
    k_exp<<<nb, 256, 0, stream>>>(araw, gmax, p, sumpart, nb);
    k_redsum<<<1, 256, 0, stream>>>(sumpart, invsum, nb);
    k_agg<<<NN / 4, 256, 0, stream>>>(p, ef, rowptr, csr, invsum, sagg, tagg);
    k_update<<<(NN + UPN - 1) / UPN, 256, 0, stream>>>(xproj, sagg, tagg, we, wo, wob, xh_next);
    xh_cur = xh_next;
  }

  // output layer (xh_cur == xh2 after 3 layers)
  k_out<<<NN / OPN, 256, 0, stream>>>(xh_cur, ow_1, ob_1, ow_2, ob_2, o_g, o_be, out);
}

// Round 2
// 917.713 us; speedup vs baseline: 2.2455x; 2.2455x over previous
//
#include <hip/hip_runtime.h>
#include <hip/hip_bf16.h>
#include <math.h>

#define NN 20000
#define EE 320000
#define HID 64
#define EHID 32
#define HEADS 4

// ---------------------------------------------------------------------------
// Node encoder: Linear(9,32)+ReLU+Linear(32,64)+LayerNorm(64). Thread per node.
__global__ __launch_bounds__(256) void k_node_enc(
    const float* __restrict__ x, const float* __restrict__ w1, const float* __restrict__ b1,
    const float* __restrict__ w2, const float* __restrict__ b2,
    const float* __restrict__ g, const float* __restrict__ beta,
    float* __restrict__ h) {
  int n = blockIdx.x * blockDim.x + threadIdx.x;
  if (n >= NN) return;
  float xin[9];
#pragma unroll
  for (int k = 0; k < 9; k++) xin[k] = x[n * 9 + k];
  float hid[32];
#pragma unroll
  for (int j = 0; j < 32; j++) {
    float a = b1[j];
#pragma unroll
    for (int k = 0; k < 9; k++) a += xin[k] * w1[k * 32 + j];
    hid[j] = fmaxf(a, 0.f);
  }
  float o[64];
  float s = 0.f;
  for (int j = 0; j < 64; j++) {
    float a = b2[j];
#pragma unroll
    for (int k = 0; k < 32; k++) a += hid[k] * w2[k * 64 + j];
    o[j] = a;
    s += a;
  }
  float m = s * (1.f / 64.f);
  float v = 0.f;
  for (int j = 0; j < 64; j++) { float d = o[j] - m; v += d * d; }
  v *= (1.f / 64.f);
  float inv = rsqrtf(v + 1e-5f);
  for (int j = 0; j < 64; j++) h[n * 64 + j] = (o[j] - m) * inv * g[j] + beta[j];
}

// ---------------------------------------------------------------------------
// Edge encoder + fused dev3: also computes ef_norm · wa_e for all 3 layers.
__global__ __launch_bounds__(256) void k_edge_enc(
    const float* __restrict__ ea, const float* __restrict__ w1, const float* __restrict__ b1,
    const float* __restrict__ w2, const float* __restrict__ b2,
    const float* __restrict__ g, const float* __restrict__ beta,
    const float* __restrict__ gat_wa,
    float* __restrict__ ef, float* __restrict__ dev3) {
  int e = blockIdx.x * blockDim.x + threadIdx.x;
  if (e >= EE) return;
  float xin[4];
#pragma unroll
  for (int k = 0; k < 4; k++) xin[k] = ea[e * 4 + k];
  float hid[16];
#pragma unroll
  for (int j = 0; j < 16; j++) {
    float a = b1[j];
#pragma unroll
    for (int k = 0; k < 4; k++) a += xin[k] * w1[k * 16 + j];
    hid[j] = fmaxf(a, 0.f);
  }
  float o[32];
  float s = 0.f;
#pragma unroll
  for (int j = 0; j < 32; j++) {
    float a = b2[j];
#pragma unroll
    for (int k = 0; k < 16; k++) a += hid[k] * w2[k * 32 + j];
    o[j] = a;
    s += a;
  }
  float m = s * (1.f / 32.f);
  float v = 0.f;
#pragma unroll
  for (int j = 0; j < 32; j++) { float d = o[j] - m; v += d * d; }
  v *= (1.f / 32.f);
  float inv = rsqrtf(v + 1e-5f);
  float d0 = 0.f, d1 = 0.f, d2 = 0.f;
#pragma unroll
  for (int j = 0; j < 32; j++) {
    float vn = (o[j] - m) * inv * g[j] + beta[j];
    ef[e * 32 + j] = vn;
    d0 += vn * gat_wa[0 * 160 + 128 + j];
    d1 += vn * gat_wa[1 * 160 + 128 + j];
    d2 += vn * gat_wa[2 * 160 + 128 + j];
  }
  dev3[e * 4 + 0] = d0;
  dev3[e * 4 + 1] = d1;
  dev3[e * 4 + 2] = d2;
}

// ---------------------------------------------------------------------------
// Risk MLP part 1: hnode = h @ ra_w1[0:64,:] + b1.  16 nodes / block.
#define RNN 16
__global__ __launch_bounds__(256) void k_risk_node(
    const float* __restrict__ h, const float* __restrict__ w1, const float* __restrict__ b1,
    float* __restrict__ hnode) {
  __shared__ float xs[RNN][64];
  int t = threadIdx.x;
  int n0 = blockIdx.x * RNN;
  for (int i = t; i < RNN * 64; i += 256) {
    int m = i >> 6, k = i & 63;
    xs[m][k] = h[(n0 + m) * 64 + k];  // NN % 16 == 0
  }
  __syncthreads();
  int j = t & 63, grp = t >> 6;
  float acc[4];
#pragma unroll
  for (int q = 0; q < 4; q++) acc[q] = b1[j];
  for (int k = 0; k < 64; k++) {
    float wv = w1[k * 64 + j];
#pragma unroll
    for (int q = 0; q < 4; q++) acc[q] += xs[grp * 4 + q][k] * wv;
  }
#pragma unroll
  for (int q = 0; q < 4; q++) hnode[(n0 + grp * 4 + q) * 64 + j] = acc[q];
}

// ---------------------------------------------------------------------------
// Risk MLP part 2: per edge rw = sigmoid(sum_j tanh(hnode[row]+ef@w1e)[j]*w2[j]+b2)
// 32 edges / block; thread = (wave w, column j); 8 edges per thread, 8-way ILP.
__global__ __launch_bounds__(256) void k_risk_edge(
    const float* __restrict__ hnode, const float* __restrict__ ef, const int* __restrict__ ei,
    const float* __restrict__ w1e, const float* __restrict__ w2, const float* __restrict__ b2_,
    float* __restrict__ rw) {
  __shared__ float hn[32][64];
  __shared__ float efs[32][32];
  int t = threadIdx.x, lane = t & 63, w = t >> 6;
  int e0 = blockIdx.x * 32;
  for (int i = t; i < 32 * 64; i += 256) {
    int el = i >> 6, k = i & 63;
    int row = ei[e0 + el];
    hn[el][k] = hnode[row * 64 + k];
  }
  for (int i = t; i < 32 * 32; i += 256) {
    int el = i >> 5, c = i & 31;
    efs[el][c] = ef[(e0 + el) * 32 + c];
  }
  __syncthreads();
  int j = lane;
  float acc[8];
#pragma unroll
  for (int q = 0; q < 8; q++) acc[q] = hn[w * 8 + q][j];
  for (int k = 0; k < 32; k++) {
    float wv = w1e[k * 64 + j];
#pragma unroll
    for (int q = 0; q < 8; q++) acc[q] += efs[w * 8 + q][k] * wv;
  }
  float w2j = w2[j];
  float b2v = b2_[0];
#pragma unroll
  for (int q = 0; q < 8; q++) {
    float v = tanhf(acc[q]) * w2j;
#pragma unroll
    for (int off = 32; off; off >>= 1) v += __shfl_xor(v, off);
    if (lane == q) rw[e0 + w * 8 + q] = 1.f / (1.f + expf(-(v + b2v)));
  }
}

// ---------------------------------------------------------------------------
// xproj = xh @ wl  -> [N, 256]. 16 nodes per block for weight reuse.
#define XPN 16
__global__ __launch_bounds__(256) void k_xproj(
    const float* __restrict__ xh, const float* __restrict__ wl,
    float* __restrict__ xproj) {
  __shared__ float xs[XPN][64];
  int t = threadIdx.x;
  int n0 = blockIdx.x * XPN;
  for (int i = t; i < XPN * 64; i += 256) {
    int m = i >> 6, k = i & 63;
    xs[m][k] = xh[(n0 + m) * 64 + k];  // NN % 16 == 0
  }
  __syncthreads();
  float acc[XPN];
#pragma unroll
  for (int m = 0; m < XPN; m++) acc[m] = 0.f;
  for (int k = 0; k < 64; k++) {
    float wv = wl[k * 256 + t];
#pragma unroll
    for (int m = 0; m < XPN; m++) acc[m] += xs[m][k] * wv;
  }
#pragma unroll
  for (int m = 0; m < XPN; m++) xproj[(n0 + m) * 256 + t] = acc[m];
}

// ---------------------------------------------------------------------------
// per-(node,head) attention dots: di = xproj[n,h]·wa_i, dj = xproj[n,h]·wa_j
__global__ __launch_bounds__(256) void k_didj(
    const float* __restrict__ xproj, const float* __restrict__ wa,
    float* __restrict__ di, float* __restrict__ dj) {
  int t = threadIdx.x, lane = t & 63, wv = t >> 6;
  int idx = blockIdx.x * 4 + wv;  // over N*HEADS
  if (idx >= NN * 4) return;
  int n = idx >> 2, head = idx & 3;
  float xv = xproj[n * 256 + head * 64 + lane];
  float vi = xv * wa[lane];
  float vj = xv * wa[64 + lane];
#pragma unroll
  for (int off = 32; off; off >>= 1) { vi += __shfl_xor(vi, off); vj += __shfl_xor(vj, off); }
  if (lane == 0) { di[idx] = vi; dj[idx] = vj; }
}

// ---------------------------------------------------------------------------
// alpha_raw per edge per head + per-block max partials (shfl-based).
__global__ __launch_bounds__(256) void k_alpha(
    const int* __restrict__ ei, const float* __restrict__ di, const float* __restrict__ dj,
    const float* __restrict__ rw, const float* __restrict__ dev3, int layer,
    float* __restrict__ araw, float* __restrict__ maxpart, int nb) {
  __shared__ float wred[4][4];
  int t = threadIdx.x, lane = t & 63, w = t >> 6;
  int e = blockIdx.x * 256 + t;  // EE % 256 == 0
  float dev = dev3[e * 4 + layer];
  int r = ei[e], cl = ei[EE + e];
  float rv = rw[e];
  float mh[4];
#pragma unroll
  for (int h = 0; h < 4; h++) {
    float z = di[r * 4 + h] + dj[cl * 4 + h] + dev;
    z = (z >= 0.f) ? z : 0.2f * z;
    z *= rv;
    araw[e * 4 + h] = z;
    mh[h] = z;
  }
#pragma unroll
  for (int h = 0; h < 4; h++) {
    float m = mh[h];
#pragma unroll
    for (int off = 32; off; off >>= 1) m = fmaxf(m, __shfl_xor(m, off));
    if (lane == 0) wred[w][h] = m;
  }
  __syncthreads();
  if (t < 4) {
    float m = fmaxf(fmaxf(wred[0][t], wred[1][t]), fmaxf(wred[2][t], wred[3][t]));
    maxpart[t * nb + blockIdx.x] = m;
  }
}

// ---------------------------------------------------------------------------
// exp pass: fuses the global-max reduction (reads maxpart) + writes sum partials.
__global__ __launch_bounds__(256) void k_exp(
    const float* __restrict__ araw, const float* __restrict__ maxpart,
    float* __restrict__ p, float* __restrict__ sumpart, int nb) {
  __shared__ float wred[4][4];
  __shared__ float gm[4];
  int t = threadIdx.x, lane = t & 63, w = t >> 6;
  float m[4] = {-1e30f, -1e30f, -1e30f, -1e30f};
  for (int i = t; i < nb; i += 256) {
#pragma unroll
    for (int h = 0; h < 4; h++) m[h] = fmaxf(m[h], maxpart[h * nb + i]);
  }
#pragma unroll
  for (int h = 0; h < 4; h++) {
    float v = m[h];
#pragma unroll
    for (int off = 32; off; off >>= 1) v = fmaxf(v, __shfl_xor(v, off));
    if (lane == 0) wred[w][h] = v;
  }
  __syncthreads();
  if (t < 4) gm[t] = fmaxf(fmaxf(wred[0][t], wred[1][t]), fmaxf(wred[2][t], wred[3][t]));
  __syncthreads();
  int e = blockIdx.x * 256 + t;
  float sh[4];
#pragma unroll
  for (int h = 0; h < 4; h++) {
    float pv = expf(araw[e * 4 + h] - gm[h]);
    p[e * 4 + h] = pv;
    sh[h] = pv;
  }
#pragma unroll
  for (int h = 0; h < 4; h++) {
    float v = sh[h];
#pragma unroll
    for (int off = 32; off; off >>= 1) v += __shfl_xor(v, off);
    if (lane == 0) wred[w][h] = v;
  }
  __syncthreads();
  if (t < 4) sumpart[t * nb + blockIdx.x] = wred[0][t] + wred[1][t] + wred[2][t] + wred[3][t];
}

// ---------------------------------------------------------------------------
// CSR build over col (reused for all 3 layers)
__global__ __launch_bounds__(256) void k_zero(int* __restrict__ counts) {
  int i = blockIdx.x * 256 + threadIdx.x;
  if (i < NN) counts[i] = 0;
}
__global__ __launch_bounds__(256) void k_hist(const int* __restrict__ ei, int* __restrict__ counts) {
  int e = blockIdx.x * 256 + threadIdx.x;
  if (e < EE) atomicAdd(&counts[ei[EE + e]], 1);
}
// shfl-based single-block scan: 1024 threads x 20 elements each.
__global__ __launch_bounds__(1024) void k_scan(
    const int* __restrict__ counts, int* __restrict__ rowptr, int* __restrict__ cursor) {
  __shared__ int wsum[16];
  int t = threadIdx.x, lane = t & 63, w = t >> 6;
  const int CH = 20;  // 1024*20 >= NN
  int base_i = t * CH;
  int local = 0;
  for (int i = 0; i < CH; i++) {
    int idx = base_i + i;
    if (idx < NN) local += counts[idx];
  }
  int v = local;
#pragma unroll
  for (int off = 1; off < 64; off <<= 1) {
    int u = __shfl_up(v, off);
    if (lane >= off) v += u;
  }
  if (lane == 63) wsum[w] = v;
  __syncthreads();
  int wbase = 0;
  for (int i = 0; i < w; i++) wbase += wsum[i];
  int run = wbase + v - local;  // exclusive prefix
  for (int i = 0; i < CH; i++) {
    int idx = base_i + i;
    if (idx < NN) {
      rowptr[idx] = run;
      cursor[idx] = run;
      run += counts[idx];
    }
  }
  if (t == 1023) rowptr[NN] = EE;
}
__global__ __launch_bounds__(256) void k_fill(
    const int* __restrict__ ei, int* __restrict__ cursor, int* __restrict__ csr) {
  int e = blockIdx.x * 256 + threadIdx.x;
  if (e < EE) {
    int pos = atomicAdd(&cursor[ei[EE + e]], 1);
    csr[pos] = e;
  }
}

// ---------------------------------------------------------------------------
// Aggregation (fuses the global inv-sum reduction): for node n,
// s[h] = sum p[e,h], t[h][c] = sum p[e,h]*ef[e,c] over incoming edges.
__global__ __launch_bounds__(256) void k_agg(
    const float* __restrict__ p, const float* __restrict__ ef,
    const int* __restrict__ rowptr, const int* __restrict__ csr,
    const float* __restrict__ sumpart, int nb,
    float* __restrict__ sagg, float* __restrict__ tagg) {
  __shared__ float wred[4][4];
  __shared__ float inv[4];
  int t = threadIdx.x, lane = t & 63, wv = t >> 6;
  float ssum[4] = {0.f, 0.f, 0.f, 0.f};
  for (int i = t; i < nb; i += 256) {
#pragma unroll
    for (int h = 0; h < 4; h++) ssum[h] += sumpart[h * nb + i];
  }
#pragma unroll
  for (int h = 0; h < 4; h++) {
    float v = ssum[h];
#pragma unroll
    for (int off = 32; off; off >>= 1) v += __shfl_xor(v, off);
    if (lane == 0) wred[wv][h] = v;
  }
  __syncthreads();
  if (t < 4) inv[t] = 1.f / (wred[0][t] + wred[1][t] + wred[2][t] + wred[3][t]);
  __syncthreads();

  int n = blockIdx.x * 4 + wv;
  if (n >= NN) return;
  int c = lane & 31, hp = lane >> 5;
  int h0 = hp * 2, h1 = h0 + 1;
  float a0 = 0.f, a1 = 0.f, s0 = 0.f, s1 = 0.f;
  int beg = rowptr[n], end = rowptr[n + 1];
  for (int i = beg; i < end; i++) {
    int e = csr[i];
    float p0 = p[e * 4 + h0];
    float p1 = p[e * 4 + h1];
    float ev = ef[e * 32 + c];
    a0 += p0 * ev;
    a1 += p1 * ev;
    s0 += p0;
    s1 += p1;
  }
  float i0 = inv[h0], i1 = inv[h1];
  tagg[n * 128 + h0 * 32 + c] = a0 * i0;
  tagg[n * 128 + h1 * 32 + c] = a1 * i1;
  if (c == 0) { sagg[n * 4 + h0] = s0 * i0; sagg[n * 4 + h1] = s1 * i1; }
}

// ---------------------------------------------------------------------------
// Node update: u = 0.25*(sum_h xproj[n,h]*s[h] + sum_h t[h]@we_h); xh = relu(u@wo+wob)
#define UPN 16
__global__ __launch_bounds__(256) void k_update(
    const float* __restrict__ xproj, const float* __restrict__ sagg,
    const float* __restrict__ tagg, const float* __restrict__ we,
    const float* __restrict__ wo, const float* __restrict__ wob,
    float* __restrict__ xh_out) {
  __shared__ float ts[UPN][128];
  __shared__ float ss[UPN][4];
  __shared__ float us[UPN][64];
  int t = threadIdx.x;
  int n0 = blockIdx.x * UPN;
  for (int i = t; i < UPN * 128; i += 256) {
    int m = i >> 7, k = i & 127;
    ts[m][k] = tagg[(n0 + m) * 128 + k];
  }
  for (int i = t; i < UPN * 4; i += 256) {
    int m = i >> 2, hh = i & 3;
    ss[m][hh] = sagg[(n0 + m) * 4 + hh];
  }
  __syncthreads();
  int j = t & 63, grp = t >> 6;
  float u[4];
#pragma unroll
  for (int q = 0; q < 4; q++) {
    int m = grp * 4 + q;
    float uu = 0.f;
#pragma unroll
    for (int h = 0; h < 4; h++)
      uu += xproj[(n0 + m) * 256 + h * 64 + j] * ss[m][h];
    u[q] = uu;
  }
  for (int h = 0; h < 4; h++) {
    for (int c = 0; c < 32; c++) {
      float wv = we[c * 256 + h * 64 + j];
#pragma unroll
      for (int q = 0; q < 4; q++) u[q] += ts[grp * 4 + q][h * 32 + c] * wv;
    }
  }
#pragma unroll
  for (int q = 0; q < 4; q++) us[grp * 4 + q][j] = 0.25f * u[q];
  __syncthreads();
  float o[4];
#pragma unroll
  for (int q = 0; q < 4; q++) o[q] = wob[j];
  for (int k = 0; k < 64; k++) {
    float wv = wo[k * 64 + j];
#pragma unroll
    for (int q = 0; q < 4; q++) o[q] += us[grp * 4 + q][k] * wv;
  }
#pragma unroll
  for (int q = 0; q < 4; q++) xh_out[(n0 + grp * 4 + q) * 64 + j] = fmaxf(o[q], 0.f);
}

// ---------------------------------------------------------------------------
// Output layer with shfl-based LayerNorm reductions. 4 nodes/block.
#define OPN 4
__global__ __launch_bounds__(256) void k_out(
    const float* __restrict__ xh, const float* __restrict__ w1, const float* __restrict__ b1,
    const float* __restrict__ w2, const float* __restrict__ b2,
    const float* __restrict__ g, const float* __restrict__ beta,
    float* __restrict__ out) {
  __shared__ float xs[OPN][64];
  __shared__ float hs[OPN][128];
  __shared__ float wp[4];
  int t = threadIdx.x, lane = t & 63, w = t >> 6;
  int n0 = blockIdx.x * OPN;
  for (int i = t; i < OPN * 64; i += 256) {
    int m = i >> 6, k = i & 63;
    xs[m][k] = xh[(n0 + m) * 64 + k];  // NN % 4 == 0
  }
  __syncthreads();
  for (int i = t; i < OPN * 128; i += 256) {
    int m = i >> 7, jj = i & 127;
    float a = b1[jj];
#pragma unroll
    for (int k = 0; k < 64; k++) a += xs[m][k] * w1[k * 128 + jj];
    hs[m][jj] = fmaxf(a, 0.f);
  }
  __syncthreads();
  float o[OPN];
#pragma unroll
  for (int m = 0; m < OPN; m++) o[m] = b2[t];
  for (int k = 0; k < 128; k++) {
    float wv = w2[k * 256 + t];
#pragma unroll
    for (int m = 0; m < OPN; m++) o[m] += hs[m][k] * wv;
  }
  float gv = g[t], bv = beta[t];
  for (int m = 0; m < OPN; m++) {
    float v = o[m];
#pragma unroll
    for (int off = 32; off; off >>= 1) v += __shfl_xor(v, off);
    if (lane == 0) wp[w] = v;
    __syncthreads();
    float mean = (wp[0] + wp[1] + wp[2] + wp[3]) * (1.f / 256.f);
    __syncthreads();
    float d = o[m] - mean;
    float vv = d * d;
#pragma unroll
    for (int off = 32; off; off >>= 1) vv += __shfl_xor(vv, off);
    if (lane == 0) wp[w] = vv;
    __syncthreads();
    float var = (wp[0] + wp[1] + wp[2] + wp[3]) * (1.f / 256.f);
    __syncthreads();
    out[(n0 + m) * 256 + t] = d * rsqrtf(var + 1e-5f) * gv + bv;
  }
}

// ---------------------------------------------------------------------------
extern "C" void kernel_launch(void* const* d_in, const int* in_sizes, int n_in,
                              void* d_out, int out_size, void* d_ws, size_t ws_size,
                              hipStream_t stream) {
  const float* x         = (const float*)d_in[0];
  const float* edge_attr = (const float*)d_in[1];
  const int*   ei        = (const int*)d_in[2];
  const float* ne_w1 = (const float*)d_in[3];
  const float* ne_b1 = (const float*)d_in[4];
  const float* ne_w2 = (const float*)d_in[5];
  const float* ne_b2 = (const float*)d_in[6];
  const float* ne_g  = (const float*)d_in[7];
  const float* ne_be = (const float*)d_in[8];
  const float* ee_w1 = (const float*)d_in[9];
  const float* ee_b1 = (const float*)d_in[10];
  const float* ee_w2 = (const float*)d_in[11];
  const float* ee_b2 = (const float*)d_in[12];
  const float* ee_g  = (const float*)d_in[13];
  const float* ee_be = (const float*)d_in[14];
  const float* ra_w1 = (const float*)d_in[15];
  const float* ra_b1 = (const float*)d_in[16];
  const float* ra_w2 = (const float*)d_in[17];
  const float* ra_b2 = (const float*)d_in[18];
  const float* gat_wl  = (const float*)d_in[19];
  const float* gat_wa  = (const float*)d_in[20];
  const float* gat_we  = (const float*)d_in[21];
  const float* gat_wo  = (const float*)d_in[22];
  const float* gat_wob = (const float*)d_in[23];
  const float* ow_1 = (const float*)d_in[24];
  const float* ob_1 = (const float*)d_in[25];
  const float* ow_2 = (const float*)d_in[26];
  const float* ob_2 = (const float*)d_in[27];
  const float* o_g  = (const float*)d_in[28];
  const float* o_be = (const float*)d_in[29];
  float* out = (float*)d_out;

  char* wsb = (char*)d_ws;
  size_t off = 0;
  auto af = [&](size_t elems) -> float* { float* p = (float*)(wsb + off); off += elems * sizeof(float); return p; };
  auto ai = [&](size_t elems) -> int*   { int*   p = (int*)(wsb + off);   off += elems * sizeof(int);   return p; };

  const int nb = EE / 256;  // 1250

  float* h      = af((size_t)NN * 64);
  float* xh2    = af((size_t)NN * 64);
  float* ef     = af((size_t)EE * 32);
  float* rw     = af((size_t)EE);
  float* dev3   = af((size_t)EE * 4);
  float* xproj  = af((size_t)NN * 256);   // also aliased as hnode before layer 0
  float* di     = af((size_t)NN * 4);
  float* dj     = af((size_t)NN * 4);
  float* araw   = af((size_t)EE * 4);
  float* p      = af((size_t)EE * 4);
  float* sagg   = af((size_t)NN * 4);
  float* tagg   = af((size_t)NN * 128);
  float* maxpart= af((size_t)4 * nb);
  float* sumpart= af((size_t)4 * nb);
  int* counts = ai(NN);
  int* rowptr = ai(NN + 1);
  int* cursor = ai(NN);
  int* csr    = ai(EE);
  float* hnode = xproj;  // alias: hnode only needed before first k_xproj
  (void)ws_size; (void)n_in; (void)in_sizes; (void)out_size;

  // encoders (edge encoder also emits dev3 = ef @ wa_e for all 3 layers)
  k_node_enc<<<(NN + 255) / 256, 256, 0, stream>>>(x, ne_w1, ne_b1, ne_w2, ne_b2, ne_g, ne_be, h);
  k_edge_enc<<<EE / 256, 256, 0, stream>>>(edge_attr, ee_w1, ee_b1, ee_w2, ee_b2, ee_g, ee_be,
                                           gat_wa, ef, dev3);
  // risk weights, decomposed: per-node matvec + per-edge matvec
  k_risk_node<<<NN / RNN, 256, 0, stream>>>(h, ra_w1, ra_b1, hnode);
  k_risk_edge<<<EE / 32, 256, 0, stream>>>(hnode, ef, ei, ra_w1 + 64 * 64, ra_w2, ra_b2, rw);
  // CSR over col
  k_zero<<<(NN + 255) / 256, 256, 0, stream>>>(counts);
  k_hist<<<EE / 256, 256, 0, stream>>>(ei, counts);
  k_scan<<<1, 1024, 0, stream>>>(counts, rowptr, cursor);
  k_fill<<<EE / 256, 256, 0, stream>>>(ei, cursor, csr);

  const float* xh_cur = h;
  float* bufs[2] = {xh2, h};
  for (int l = 0; l < 3; l++) {
    const float* wl  = gat_wl + (size_t)l * 64 * 256;
    const float* wa  = gat_wa + (size_t)l * 160;
    const float* we  = gat_we + (size_t)l * 32 * 256;
    const float* wo  = gat_wo + (size_t)l * 64 * 64;
    const float* wob = gat_wob + (size_t)l * 64;
    float* xh_next = bufs[l & 1];

    k_xproj<<<NN / XPN, 256, 0, stream>>>(xh_cur, wl, xproj);
    k_didj<<<NN, 256, 0, stream>>>(xproj, wa, di, dj);
    k_alpha<<<nb, 256, 0, stream>>>(ei, di, dj, rw, dev3, l, araw, maxpart, nb);
    k_exp<<<nb, 256, 0, stream>>>(araw, maxpart, p, sumpart, nb);
    k_agg<<<NN / 4, 256, 0, stream>>>(p, ef, rowptr, csr, sumpart, nb, sagg, tagg);
    k_update<<<NN / UPN, 256, 0, stream>>>(xproj, sagg, tagg, we, wo, wob, xh_next);
    xh_cur = xh_next;
  }

  // output layer (xh_cur == xh2 after 3 layers)
  k_out<<<NN / OPN, 256, 0, stream>>>(xh_cur, ow_1, ob_1, ow_2, ob_2, o_g, o_be, out);
}

// Round 3
// 705.347 us; speedup vs baseline: 2.9216x; 1.3011x over previous
//
#include <hip/hip_runtime.h>
#include <math.h>

#define NN 20000
#define EE 320000
#define HID 64
#define EHID 32
#define HEADS 4

// ---------------------------------------------------------------------------
// Node encoder: Linear(9,32)+ReLU+Linear(32,64)+LayerNorm(64). Thread per node.
__global__ __launch_bounds__(256) void k_node_enc(
    const float* __restrict__ x, const float* __restrict__ w1, const float* __restrict__ b1,
    const float* __restrict__ w2, const float* __restrict__ b2,
    const float* __restrict__ g, const float* __restrict__ beta,
    float* __restrict__ h) {
  int n = blockIdx.x * blockDim.x + threadIdx.x;
  if (n >= NN) return;
  float xin[9];
#pragma unroll
  for (int k = 0; k < 9; k++) xin[k] = x[n * 9 + k];
  float hid[32];
#pragma unroll
  for (int j = 0; j < 32; j++) {
    float a = b1[j];
#pragma unroll
    for (int k = 0; k < 9; k++) a += xin[k] * w1[k * 32 + j];
    hid[j] = fmaxf(a, 0.f);
  }
  float o[64];
  float s = 0.f;
  for (int j = 0; j < 64; j++) {
    float a = b2[j];
#pragma unroll
    for (int k = 0; k < 32; k++) a += hid[k] * w2[k * 64 + j];
    o[j] = a;
    s += a;
  }
  float m = s * (1.f / 64.f);
  float v = 0.f;
  for (int j = 0; j < 64; j++) { float d = o[j] - m; v += d * d; }
  v *= (1.f / 64.f);
  float inv = rsqrtf(v + 1e-5f);
#pragma unroll
  for (int j4 = 0; j4 < 16; j4++) {
    float4 r;
    r.x = (o[j4 * 4 + 0] - m) * inv * g[j4 * 4 + 0] + beta[j4 * 4 + 0];
    r.y = (o[j4 * 4 + 1] - m) * inv * g[j4 * 4 + 1] + beta[j4 * 4 + 1];
    r.z = (o[j4 * 4 + 2] - m) * inv * g[j4 * 4 + 2] + beta[j4 * 4 + 2];
    r.w = (o[j4 * 4 + 3] - m) * inv * g[j4 * 4 + 3] + beta[j4 * 4 + 3];
    ((float4*)&h[n * 64])[j4] = r;
  }
}

// ---------------------------------------------------------------------------
// Edge encoder + fused dev3 (ef_norm · wa_e for all 3 layers). Thread per edge.
__global__ __launch_bounds__(256) void k_edge_enc(
    const float* __restrict__ ea, const float* __restrict__ w1, const float* __restrict__ b1,
    const float* __restrict__ w2, const float* __restrict__ b2,
    const float* __restrict__ g, const float* __restrict__ beta,
    const float* __restrict__ gat_wa,
    float* __restrict__ ef, float* __restrict__ dev3) {
  int e = blockIdx.x * blockDim.x + threadIdx.x;
  if (e >= EE) return;
  float4 xin = ((const float4*)ea)[e];
  float hid[16];
#pragma unroll
  for (int j = 0; j < 16; j++) {
    float a = b1[j];
    a += xin.x * w1[0 * 16 + j];
    a += xin.y * w1[1 * 16 + j];
    a += xin.z * w1[2 * 16 + j];
    a += xin.w * w1[3 * 16 + j];
    hid[j] = fmaxf(a, 0.f);
  }
  float o[32];
  float s = 0.f;
#pragma unroll
  for (int j = 0; j < 32; j++) {
    float a = b2[j];
#pragma unroll
    for (int k = 0; k < 16; k++) a += hid[k] * w2[k * 32 + j];
    o[j] = a;
    s += a;
  }
  float m = s * (1.f / 32.f);
  float v = 0.f;
#pragma unroll
  for (int j = 0; j < 32; j++) { float d = o[j] - m; v += d * d; }
  v *= (1.f / 32.f);
  float inv = rsqrtf(v + 1e-5f);
  float d0 = 0.f, d1 = 0.f, d2 = 0.f;
  float vn[32];
#pragma unroll
  for (int j = 0; j < 32; j++) {
    vn[j] = (o[j] - m) * inv * g[j] + beta[j];
    d0 += vn[j] * gat_wa[0 * 160 + 128 + j];
    d1 += vn[j] * gat_wa[1 * 160 + 128 + j];
    d2 += vn[j] * gat_wa[2 * 160 + 128 + j];
  }
#pragma unroll
  for (int j4 = 0; j4 < 8; j4++) {
    float4 r;
    r.x = vn[j4 * 4 + 0]; r.y = vn[j4 * 4 + 1]; r.z = vn[j4 * 4 + 2]; r.w = vn[j4 * 4 + 3];
    ((float4*)&ef[e * 32])[j4] = r;
  }
  float4 dv; dv.x = d0; dv.y = d1; dv.z = d2; dv.w = 0.f;
  ((float4*)dev3)[e] = dv;
}

// ---------------------------------------------------------------------------
// Risk MLP part 1: hnode = h @ ra_w1[0:64,:] + b1.  16 nodes / block.
#define RNN 16
__global__ __launch_bounds__(256) void k_risk_node(
    const float* __restrict__ h, const float* __restrict__ w1, const float* __restrict__ b1,
    float* __restrict__ hnode) {
  __shared__ float xs[RNN][64];
  int t = threadIdx.x;
  int n0 = blockIdx.x * RNN;
  const float4* h4 = (const float4*)h;
  for (int i = t; i < RNN * 16; i += 256) {
    int m = i >> 4, k4 = i & 15;
    ((float4*)&xs[m][0])[k4] = h4[(n0 + m) * 16 + k4];
  }
  __syncthreads();
  int j = t & 63, grp = t >> 6;
  float acc[4];
#pragma unroll
  for (int q = 0; q < 4; q++) acc[q] = b1[j];
  for (int k = 0; k < 64; k++) {
    float wv = w1[k * 64 + j];
#pragma unroll
    for (int q = 0; q < 4; q++) acc[q] += xs[grp * 4 + q][k] * wv;
  }
#pragma unroll
  for (int q = 0; q < 4; q++) hnode[(n0 + grp * 4 + q) * 64 + j] = acc[q];
}

// ---------------------------------------------------------------------------
// Risk MLP part 2, zero-LDS layout: 8-lane group per edge; lane s owns output
// columns j = s*8..s*8+7; the edge's ef row (32 f) lives in the lane's VGPRs.
__global__ __launch_bounds__(256) void k_risk_edge(
    const float* __restrict__ hnode, const float* __restrict__ ef, const int* __restrict__ ei,
    const float* __restrict__ w1e, const float* __restrict__ w2, const float* __restrict__ b2_,
    float* __restrict__ rw) {
  int t = threadIdx.x, lane = t & 63, w = t >> 6;
  int g = lane >> 3, s = lane & 7;
  int e = blockIdx.x * 32 + w * 8 + g;
  int row = ei[e];
  const float4* hnode4 = (const float4*)hnode;
  const float4* ef4 = (const float4*)ef;
  const float4* w1e4 = (const float4*)w1e;
  const float4* w24 = (const float4*)w2;
  // ef row into registers (statically indexed -> VGPRs)
  float ev[32];
#pragma unroll
  for (int i = 0; i < 8; i++) {
    float4 tmp = ef4[e * 8 + i];
    ev[i * 4 + 0] = tmp.x; ev[i * 4 + 1] = tmp.y; ev[i * 4 + 2] = tmp.z; ev[i * 4 + 3] = tmp.w;
  }
  float acc[8];
  {
    float4 ha = hnode4[row * 16 + s * 2];
    float4 hb = hnode4[row * 16 + s * 2 + 1];
    acc[0] = ha.x; acc[1] = ha.y; acc[2] = ha.z; acc[3] = ha.w;
    acc[4] = hb.x; acc[5] = hb.y; acc[6] = hb.z; acc[7] = hb.w;
  }
#pragma unroll
  for (int k = 0; k < 32; k++) {
    float4 wa4 = w1e4[k * 16 + s * 2];
    float4 wb4 = w1e4[k * 16 + s * 2 + 1];
    float ek = ev[k];
    acc[0] += ek * wa4.x; acc[1] += ek * wa4.y; acc[2] += ek * wa4.z; acc[3] += ek * wa4.w;
    acc[4] += ek * wb4.x; acc[5] += ek * wb4.y; acc[6] += ek * wb4.z; acc[7] += ek * wb4.w;
  }
  float4 w2a = w24[s * 2], w2b = w24[s * 2 + 1];
  float vsum = tanhf(acc[0]) * w2a.x + tanhf(acc[1]) * w2a.y +
               tanhf(acc[2]) * w2a.z + tanhf(acc[3]) * w2a.w +
               tanhf(acc[4]) * w2b.x + tanhf(acc[5]) * w2b.y +
               tanhf(acc[6]) * w2b.z + tanhf(acc[7]) * w2b.w;
  vsum += __shfl_xor(vsum, 1);
  vsum += __shfl_xor(vsum, 2);
  vsum += __shfl_xor(vsum, 4);
  if (s == 0) rw[e] = 1.f / (1.f + expf(-(vsum + b2_[0])));
}

// ---------------------------------------------------------------------------
// xproj = xh @ wl -> [N,256], with fused di/dj (wave w == head w).
#define XPN 16
__global__ __launch_bounds__(256) void k_xproj(
    const float* __restrict__ xh, const float* __restrict__ wl, const float* __restrict__ wa,
    float* __restrict__ xproj, float* __restrict__ di, float* __restrict__ dj) {
  __shared__ float xs[XPN][64];
  int t = threadIdx.x, lane = t & 63, w = t >> 6;
  int n0 = blockIdx.x * XPN;
  const float4* xh4 = (const float4*)xh;
  for (int i = t; i < XPN * 16; i += 256) {
    int m = i >> 4, k4 = i & 15;
    ((float4*)&xs[m][0])[k4] = xh4[(n0 + m) * 16 + k4];
  }
  __syncthreads();
  float acc[XPN];
#pragma unroll
  for (int m = 0; m < XPN; m++) acc[m] = 0.f;
  for (int k = 0; k < 64; k++) {
    float wv = wl[k * 256 + t];
#pragma unroll
    for (int m = 0; m < XPN; m++) acc[m] += xs[m][k] * wv;
  }
  float wai = wa[lane], waj = wa[64 + lane];
#pragma unroll
  for (int m = 0; m < XPN; m++) {
    xproj[(n0 + m) * 256 + t] = acc[m];
    float vi = acc[m] * wai;
    float vj = acc[m] * waj;
#pragma unroll
    for (int off = 32; off; off >>= 1) { vi += __shfl_xor(vi, off); vj += __shfl_xor(vj, off); }
    if (lane == 0) { di[(n0 + m) * 4 + w] = vi; dj[(n0 + m) * 4 + w] = vj; }
  }
}

// ---------------------------------------------------------------------------
// alpha + exp fused (softmax is shift-invariant; |z| is O(5) here so exp(z)
// directly is safe): writes p = exp(z) and per-block sum partials.
__global__ __launch_bounds__(256) void k_alphaexp(
    const int* __restrict__ ei, const float* __restrict__ di, const float* __restrict__ dj,
    const float* __restrict__ rw, const float* __restrict__ dev3, int layer,
    float* __restrict__ p, float* __restrict__ sumpart, int nb) {
  __shared__ float wred[4][4];
  int t = threadIdx.x, lane = t & 63, w = t >> 6;
  int e = blockIdx.x * 256 + t;  // EE % 256 == 0
  float4 dv = ((const float4*)dev3)[e];
  float dev = (layer == 0) ? dv.x : ((layer == 1) ? dv.y : dv.z);
  int r = ei[e], cl = ei[EE + e];
  float rv = rw[e];
  float4 dir = ((const float4*)di)[r];
  float4 djc = ((const float4*)dj)[cl];
  float z0 = dir.x + djc.x + dev, z1 = dir.y + djc.y + dev;
  float z2 = dir.z + djc.z + dev, z3 = dir.w + djc.w + dev;
  z0 = ((z0 >= 0.f) ? z0 : 0.2f * z0) * rv;
  z1 = ((z1 >= 0.f) ? z1 : 0.2f * z1) * rv;
  z2 = ((z2 >= 0.f) ? z2 : 0.2f * z2) * rv;
  z3 = ((z3 >= 0.f) ? z3 : 0.2f * z3) * rv;
  float4 pv;
  pv.x = expf(z0); pv.y = expf(z1); pv.z = expf(z2); pv.w = expf(z3);
  ((float4*)p)[e] = pv;
  float sh[4] = {pv.x, pv.y, pv.z, pv.w};
#pragma unroll
  for (int h = 0; h < 4; h++) {
    float v = sh[h];
#pragma unroll
    for (int off = 32; off; off >>= 1) v += __shfl_xor(v, off);
    if (lane == 0) wred[w][h] = v;
  }
  __syncthreads();
  if (t < 4) sumpart[t * nb + blockIdx.x] = wred[0][t] + wred[1][t] + wred[2][t] + wred[3][t];
}

// tiny: inv[h] = 1 / sum(sumpart[h, :])
__global__ __launch_bounds__(256) void k_sinv(
    const float* __restrict__ sumpart, float* __restrict__ inv, int nb) {
  __shared__ float wred[4][4];
  int t = threadIdx.x, lane = t & 63, w = t >> 6;
  float s[4] = {0.f, 0.f, 0.f, 0.f};
  for (int i = t; i < nb; i += 256) {
#pragma unroll
    for (int h = 0; h < 4; h++) s[h] += sumpart[h * nb + i];
  }
#pragma unroll
  for (int h = 0; h < 4; h++) {
    float v = s[h];
#pragma unroll
    for (int off = 32; off; off >>= 1) v += __shfl_xor(v, off);
    if (lane == 0) wred[w][h] = v;
  }
  __syncthreads();
  if (t < 4) inv[t] = 1.f / (wred[0][t] + wred[1][t] + wred[2][t] + wred[3][t]);
}

// ---------------------------------------------------------------------------
// CSR build over col (reused for all 3 layers)
__global__ __launch_bounds__(256) void k_hist(const int* __restrict__ ei, int* __restrict__ counts) {
  int e = blockIdx.x * 256 + threadIdx.x;
  if (e < EE) atomicAdd(&counts[ei[EE + e]], 1);
}
__global__ __launch_bounds__(1024) void k_scan(
    const int* __restrict__ counts, int* __restrict__ rowptr, int* __restrict__ cursor) {
  __shared__ int wsum[16];
  int t = threadIdx.x, lane = t & 63, w = t >> 6;
  const int CH = 20;  // 1024*20 >= NN
  int base_i = t * CH;
  int local = 0;
  for (int i = 0; i < CH; i++) {
    int idx = base_i + i;
    if (idx < NN) local += counts[idx];
  }
  int v = local;
#pragma unroll
  for (int off = 1; off < 64; off <<= 1) {
    int u = __shfl_up(v, off);
    if (lane >= off) v += u;
  }
  if (lane == 63) wsum[w] = v;
  __syncthreads();
  int wbase = 0;
  for (int i = 0; i < w; i++) wbase += wsum[i];
  int run = wbase + v - local;  // exclusive prefix
  for (int i = 0; i < CH; i++) {
    int idx = base_i + i;
    if (idx < NN) {
      rowptr[idx] = run;
      cursor[idx] = run;
      run += counts[idx];
    }
  }
  if (t == 1023) rowptr[NN] = EE;
}
__global__ __launch_bounds__(256) void k_fill(
    const int* __restrict__ ei, int* __restrict__ cursor, int* __restrict__ csr) {
  int e = blockIdx.x * 256 + threadIdx.x;
  if (e < EE) {
    int pos = atomicAdd(&cursor[ei[EE + e]], 1);
    csr[pos] = e;
  }
}

// ---------------------------------------------------------------------------
// Aggregation: wave per node; s[h] = sum p[e,h], t[h][c] = sum p[e,h]*ef[e,c].
__global__ __launch_bounds__(256) void k_agg(
    const float* __restrict__ p, const float* __restrict__ ef,
    const int* __restrict__ rowptr, const int* __restrict__ csr,
    const float* __restrict__ inv,
    float* __restrict__ sagg, float* __restrict__ tagg) {
  int t = threadIdx.x, lane = t & 63, wv = t >> 6;
  int n = blockIdx.x * 4 + wv;
  int c = lane & 31, hp = lane >> 5;
  float a0 = 0.f, a1 = 0.f, s0 = 0.f, s1 = 0.f;
  int beg = rowptr[n], end = rowptr[n + 1];
  int i = beg;
  for (; i + 1 < end; i += 2) {
    int ea = csr[i], eb = csr[i + 1];
    float4 pa = ((const float4*)p)[ea];
    float4 pb = ((const float4*)p)[eb];
    float eva = ef[ea * 32 + c];
    float evb = ef[eb * 32 + c];
    float p0a = hp ? pa.z : pa.x, p1a = hp ? pa.w : pa.y;
    float p0b = hp ? pb.z : pb.x, p1b = hp ? pb.w : pb.y;
    a0 += p0a * eva + p0b * evb;
    a1 += p1a * eva + p1b * evb;
    s0 += p0a + p0b;
    s1 += p1a + p1b;
  }
  if (i < end) {
    int ea = csr[i];
    float4 pa = ((const float4*)p)[ea];
    float eva = ef[ea * 32 + c];
    float p0a = hp ? pa.z : pa.x, p1a = hp ? pa.w : pa.y;
    a0 += p0a * eva; a1 += p1a * eva; s0 += p0a; s1 += p1a;
  }
  int h0 = hp * 2, h1 = h0 + 1;
  float i0 = inv[h0], i1 = inv[h1];
  tagg[n * 128 + h0 * 32 + c] = a0 * i0;
  tagg[n * 128 + h1 * 32 + c] = a1 * i1;
  if (c == 0) { sagg[n * 4 + h0] = s0 * i0; sagg[n * 4 + h1] = s1 * i1; }
}

// ---------------------------------------------------------------------------
// Node update: u = 0.25*(sum_h xproj[n,h]*s[h] + sum_h t[h]@we_h); xh = relu(u@wo+wob)
#define UPN 16
__global__ __launch_bounds__(256) void k_update(
    const float* __restrict__ xproj, const float* __restrict__ sagg,
    const float* __restrict__ tagg, const float* __restrict__ we,
    const float* __restrict__ wo, const float* __restrict__ wob,
    float* __restrict__ xh_out) {
  __shared__ float ts[UPN][128];
  __shared__ float ss[UPN][4];
  __shared__ float us[UPN][64];
  int t = threadIdx.x;
  int n0 = blockIdx.x * UPN;
  const float4* tagg4 = (const float4*)tagg;
  for (int i = t; i < UPN * 32; i += 256) {
    int m = i >> 5, k4 = i & 31;
    ((float4*)&ts[m][0])[k4] = tagg4[(n0 + m) * 32 + k4];
  }
  if (t < UPN * 4) ss[t >> 2][t & 3] = sagg[n0 * 4 + t];
  __syncthreads();
  int j = t & 63, grp = t >> 6;
  float u[4];
#pragma unroll
  for (int q = 0; q < 4; q++) {
    int m = grp * 4 + q;
    float uu = 0.f;
#pragma unroll
    for (int h = 0; h < 4; h++)
      uu += xproj[(n0 + m) * 256 + h * 64 + j] * ss[m][h];
    u[q] = uu;
  }
  for (int h = 0; h < 4; h++) {
    for (int c = 0; c < 32; c++) {
      float wv = we[c * 256 + h * 64 + j];
#pragma unroll
      for (int q = 0; q < 4; q++) u[q] += ts[grp * 4 + q][h * 32 + c] * wv;
    }
  }
#pragma unroll
  for (int q = 0; q < 4; q++) us[grp * 4 + q][j] = 0.25f * u[q];
  __syncthreads();
  float o[4];
#pragma unroll
  for (int q = 0; q < 4; q++) o[q] = wob[j];
  for (int k = 0; k < 64; k++) {
    float wv = wo[k * 64 + j];
#pragma unroll
    for (int q = 0; q < 4; q++) o[q] += us[grp * 4 + q][k] * wv;
  }
#pragma unroll
  for (int q = 0; q < 4; q++) xh_out[(n0 + grp * 4 + q) * 64 + j] = fmaxf(o[q], 0.f);
}

// ---------------------------------------------------------------------------
// Output layer: Linear(64,128)+ReLU+Linear(128,256)+LayerNorm(256). 8 nodes/block.
#define OPN 8
__global__ __launch_bounds__(256) void k_out(
    const float* __restrict__ xh, const float* __restrict__ w1, const float* __restrict__ b1,
    const float* __restrict__ w2, const float* __restrict__ b2,
    const float* __restrict__ g, const float* __restrict__ beta,
    float* __restrict__ out) {
  __shared__ float xs[OPN][64];
  __shared__ float hs[OPN][128];
  __shared__ float wp[4], wq[4];
  int t = threadIdx.x, lane = t & 63, w = t >> 6;
  int n0 = blockIdx.x * OPN;
  const float4* xh4 = (const float4*)xh;
  for (int i = t; i < OPN * 16; i += 256) {
    int m = i >> 4, k4 = i & 15;
    ((float4*)&xs[m][0])[k4] = xh4[(n0 + m) * 16 + k4];
  }
  __syncthreads();
  for (int i = t; i < OPN * 128; i += 256) {
    int m = i >> 7, jj = i & 127;
    float a = b1[jj];
#pragma unroll
    for (int k = 0; k < 64; k++) a += xs[m][k] * w1[k * 128 + jj];
    hs[m][jj] = fmaxf(a, 0.f);
  }
  __syncthreads();
  float o[OPN];
#pragma unroll
  for (int m = 0; m < OPN; m++) o[m] = b2[t];
  for (int k = 0; k < 128; k++) {
    float wv = w2[k * 256 + t];
#pragma unroll
    for (int m = 0; m < OPN; m++) o[m] += hs[m][k] * wv;
  }
  float gv = g[t], bv = beta[t];
#pragma unroll
  for (int m = 0; m < OPN; m++) {
    float v = o[m], vv = o[m] * o[m];
#pragma unroll
    for (int off = 32; off; off >>= 1) { v += __shfl_xor(v, off); vv += __shfl_xor(vv, off); }
    if (lane == 0) { wp[w] = v; wq[w] = vv; }
    __syncthreads();
    float mean = (wp[0] + wp[1] + wp[2] + wp[3]) * (1.f / 256.f);
    float ex2 = (wq[0] + wq[1] + wq[2] + wq[3]) * (1.f / 256.f);
    float var = ex2 - mean * mean;
    __syncthreads();
    out[(n0 + m) * 256 + t] = (o[m] - mean) * rsqrtf(var + 1e-5f) * gv + bv;
  }
}

// ---------------------------------------------------------------------------
extern "C" void kernel_launch(void* const* d_in, const int* in_sizes, int n_in,
                              void* d_out, int out_size, void* d_ws, size_t ws_size,
                              hipStream_t stream) {
  const float* x         = (const float*)d_in[0];
  const float* edge_attr = (const float*)d_in[1];
  const int*   ei        = (const int*)d_in[2];
  const float* ne_w1 = (const float*)d_in[3];
  const float* ne_b1 = (const float*)d_in[4];
  const float* ne_w2 = (const float*)d_in[5];
  const float* ne_b2 = (const float*)d_in[6];
  const float* ne_g  = (const float*)d_in[7];
  const float* ne_be = (const float*)d_in[8];
  const float* ee_w1 = (const float*)d_in[9];
  const float* ee_b1 = (const float*)d_in[10];
  const float* ee_w2 = (const float*)d_in[11];
  const float* ee_b2 = (const float*)d_in[12];
  const float* ee_g  = (const float*)d_in[13];
  const float* ee_be = (const float*)d_in[14];
  const float* ra_w1 = (const float*)d_in[15];
  const float* ra_b1 = (const float*)d_in[16];
  const float* ra_w2 = (const float*)d_in[17];
  const float* ra_b2 = (const float*)d_in[18];
  const float* gat_wl  = (const float*)d_in[19];
  const float* gat_wa  = (const float*)d_in[20];
  const float* gat_we  = (const float*)d_in[21];
  const float* gat_wo  = (const float*)d_in[22];
  const float* gat_wob = (const float*)d_in[23];
  const float* ow_1 = (const float*)d_in[24];
  const float* ob_1 = (const float*)d_in[25];
  const float* ow_2 = (const float*)d_in[26];
  const float* ob_2 = (const float*)d_in[27];
  const float* o_g  = (const float*)d_in[28];
  const float* o_be = (const float*)d_in[29];
  float* out = (float*)d_out;

  char* wsb = (char*)d_ws;
  size_t off = 0;
  auto af = [&](size_t elems) -> float* { float* p = (float*)(wsb + off); off += elems * sizeof(float); return p; };
  auto ai = [&](size_t elems) -> int*   { int*   p = (int*)(wsb + off);   off += elems * sizeof(int);   return p; };

  const int nb = EE / 256;  // 1250

  float* h      = af((size_t)NN * 64);
  float* xh2    = af((size_t)NN * 64);
  float* ef     = af((size_t)EE * 32);
  float* rw     = af((size_t)EE);
  float* dev3   = af((size_t)EE * 4);
  float* xproj  = af((size_t)NN * 256);   // aliased as hnode before layer 0
  float* di     = af((size_t)NN * 4);
  float* dj     = af((size_t)NN * 4);
  float* p      = af((size_t)EE * 4);
  float* sagg   = af((size_t)NN * 4);
  float* tagg   = af((size_t)NN * 128);
  float* sumpart= af((size_t)4 * nb);
  float* invs   = af(4);
  int* counts = ai(NN);
  int* rowptr = ai(NN + 1);
  int* cursor = ai(NN);
  int* csr    = ai(EE);
  float* hnode = xproj;  // alias: consumed before first k_xproj
  (void)ws_size; (void)n_in; (void)in_sizes; (void)out_size;

  // encoders
  k_node_enc<<<(NN + 255) / 256, 256, 0, stream>>>(x, ne_w1, ne_b1, ne_w2, ne_b2, ne_g, ne_be, h);
  k_edge_enc<<<EE / 256, 256, 0, stream>>>(edge_attr, ee_w1, ee_b1, ee_w2, ee_b2, ee_g, ee_be,
                                           gat_wa, ef, dev3);
  // risk weights
  k_risk_node<<<NN / RNN, 256, 0, stream>>>(h, ra_w1, ra_b1, hnode);
  k_risk_edge<<<EE / 32, 256, 0, stream>>>(hnode, ef, ei, ra_w1 + 64 * 64, ra_w2, ra_b2, rw);
  // CSR over col
  hipMemsetAsync(counts, 0, NN * sizeof(int), stream);
  k_hist<<<EE / 256, 256, 0, stream>>>(ei, counts);
  k_scan<<<1, 1024, 0, stream>>>(counts, rowptr, cursor);
  k_fill<<<EE / 256, 256, 0, stream>>>(ei, cursor, csr);

  const float* xh_cur = h;
  float* bufs[2] = {xh2, h};
  for (int l = 0; l < 3; l++) {
    const float* wl  = gat_wl + (size_t)l * 64 * 256;
    const float* wa  = gat_wa + (size_t)l * 160;
    const float* we  = gat_we + (size_t)l * 32 * 256;
    const float* wo  = gat_wo + (size_t)l * 64 * 64;
    const float* wob = gat_wob + (size_t)l * 64;
    float* xh_next = bufs[l & 1];

    k_xproj<<<NN / XPN, 256, 0, stream>>>(xh_cur, wl, wa, xproj, di, dj);
    k_alphaexp<<<nb, 256, 0, stream>>>(ei, di, dj, rw, dev3, l, p, sumpart, nb);
    k_sinv<<<1, 256, 0, stream>>>(sumpart, invs, nb);
    k_agg<<<NN / 4, 256, 0, stream>>>(p, ef, rowptr, csr, invs, sagg, tagg);
    k_update<<<NN / UPN, 256, 0, stream>>>(xproj, sagg, tagg, we, wo, wob, xh_next);
    xh_cur = xh_next;
  }

  // output layer (xh_cur == xh2 after 3 layers)
  k_out<<<NN / OPN, 256, 0, stream>>>(xh_cur, ow_1, ob_1, ow_2, ob_2, o_g, o_be, out);
}

// Round 4
// 618.248 us; speedup vs baseline: 3.3332x; 1.1409x over previous
//
#include <hip/hip_runtime.h>
#include <math.h>

#define NN 20000
#define EE 320000
#define HID 64
#define EHID 32
#define HEADS 4

__device__ __forceinline__ float fast_tanh(float x) {
  float e = __expf(2.f * x);   // v_mul + v_exp_f32
  return 1.f - 2.f * __builtin_amdgcn_rcpf(e + 1.f);
}
__device__ __forceinline__ float fast_sigmoid(float x) {
  return __builtin_amdgcn_rcpf(1.f + __expf(-x));
}

// ---------------------------------------------------------------------------
// Node encoder: Linear(9,32)+ReLU+Linear(32,64)+LayerNorm(64). Thread per node.
__global__ __launch_bounds__(256) void k_node_enc(
    const float* __restrict__ x, const float* __restrict__ w1, const float* __restrict__ b1,
    const float* __restrict__ w2, const float* __restrict__ b2,
    const float* __restrict__ g, const float* __restrict__ beta,
    float* __restrict__ h) {
  int n = blockIdx.x * blockDim.x + threadIdx.x;
  if (n >= NN) return;
  float xin[9];
#pragma unroll
  for (int k = 0; k < 9; k++) xin[k] = x[n * 9 + k];
  float hid[32];
#pragma unroll
  for (int j = 0; j < 32; j++) {
    float a = b1[j];
#pragma unroll
    for (int k = 0; k < 9; k++) a += xin[k] * w1[k * 32 + j];
    hid[j] = fmaxf(a, 0.f);
  }
  float o[64];
  float s = 0.f;
  for (int j = 0; j < 64; j++) {
    float a = b2[j];
#pragma unroll
    for (int k = 0; k < 32; k++) a += hid[k] * w2[k * 64 + j];
    o[j] = a;
    s += a;
  }
  float m = s * (1.f / 64.f);
  float v = 0.f;
  for (int j = 0; j < 64; j++) { float d = o[j] - m; v += d * d; }
  v *= (1.f / 64.f);
  float inv = rsqrtf(v + 1e-5f);
#pragma unroll
  for (int j4 = 0; j4 < 16; j4++) {
    float4 r;
    r.x = (o[j4 * 4 + 0] - m) * inv * g[j4 * 4 + 0] + beta[j4 * 4 + 0];
    r.y = (o[j4 * 4 + 1] - m) * inv * g[j4 * 4 + 1] + beta[j4 * 4 + 1];
    r.z = (o[j4 * 4 + 2] - m) * inv * g[j4 * 4 + 2] + beta[j4 * 4 + 2];
    r.w = (o[j4 * 4 + 3] - m) * inv * g[j4 * 4 + 3] + beta[j4 * 4 + 3];
    ((float4*)&h[n * 64])[j4] = r;
  }
}

// ---------------------------------------------------------------------------
// Edge encoder + fused dev3 + fused CSR histogram. Thread per edge.
__global__ __launch_bounds__(256) void k_edge_enc(
    const float* __restrict__ ea, const float* __restrict__ w1, const float* __restrict__ b1,
    const float* __restrict__ w2, const float* __restrict__ b2,
    const float* __restrict__ g, const float* __restrict__ beta,
    const float* __restrict__ gat_wa, const int* __restrict__ ei,
    float* __restrict__ ef, float* __restrict__ dev3, int* __restrict__ counts) {
  int e = blockIdx.x * blockDim.x + threadIdx.x;
  if (e >= EE) return;
  atomicAdd(&counts[ei[EE + e]], 1);
  float4 xin = ((const float4*)ea)[e];
  float hid[16];
#pragma unroll
  for (int j = 0; j < 16; j++) {
    float a = b1[j];
    a += xin.x * w1[0 * 16 + j];
    a += xin.y * w1[1 * 16 + j];
    a += xin.z * w1[2 * 16 + j];
    a += xin.w * w1[3 * 16 + j];
    hid[j] = fmaxf(a, 0.f);
  }
  float o[32];
  float s = 0.f;
#pragma unroll
  for (int j = 0; j < 32; j++) {
    float a = b2[j];
#pragma unroll
    for (int k = 0; k < 16; k++) a += hid[k] * w2[k * 32 + j];
    o[j] = a;
    s += a;
  }
  float m = s * (1.f / 32.f);
  float v = 0.f;
#pragma unroll
  for (int j = 0; j < 32; j++) { float d = o[j] - m; v += d * d; }
  v *= (1.f / 32.f);
  float inv = rsqrtf(v + 1e-5f);
  float d0 = 0.f, d1 = 0.f, d2 = 0.f;
  float vn[32];
#pragma unroll
  for (int j = 0; j < 32; j++) {
    vn[j] = (o[j] - m) * inv * g[j] + beta[j];
    d0 += vn[j] * gat_wa[0 * 160 + 128 + j];
    d1 += vn[j] * gat_wa[1 * 160 + 128 + j];
    d2 += vn[j] * gat_wa[2 * 160 + 128 + j];
  }
#pragma unroll
  for (int j4 = 0; j4 < 8; j4++) {
    float4 r;
    r.x = vn[j4 * 4 + 0]; r.y = vn[j4 * 4 + 1]; r.z = vn[j4 * 4 + 2]; r.w = vn[j4 * 4 + 3];
    ((float4*)&ef[e * 32])[j4] = r;
  }
  float4 dv; dv.x = d0; dv.y = d1; dv.z = d2; dv.w = 0.f;
  ((float4*)dev3)[e] = dv;
}

// ---------------------------------------------------------------------------
// Risk MLP part 1: hnode = h @ ra_w1[0:64,:] + b1. 16 nodes/block, transposed LDS.
__global__ __launch_bounds__(256) void k_risk_node(
    const float* __restrict__ h, const float* __restrict__ w1, const float* __restrict__ b1,
    float* __restrict__ hnode) {
  __shared__ float xsT[64][20];
  int t = threadIdx.x;
  int n0 = blockIdx.x * 16;
  const float4* h4 = (const float4*)h;
  {
    int m = t & 15, k4 = t >> 4;  // 256 threads == 256 float4s
    float4 xv = h4[(n0 + m) * 16 + k4];
    xsT[k4 * 4 + 0][m] = xv.x;
    xsT[k4 * 4 + 1][m] = xv.y;
    xsT[k4 * 4 + 2][m] = xv.z;
    xsT[k4 * 4 + 3][m] = xv.w;
  }
  __syncthreads();
  int j = t & 63, grp = t >> 6;
  float bv = b1[j];
  float a0 = bv, a1 = bv, a2 = bv, a3 = bv;
  for (int k = 0; k < 64; k++) {
    float wv = w1[k * 64 + j];
    float4 xv = *(const float4*)&xsT[k][grp * 4];
    a0 += xv.x * wv; a1 += xv.y * wv; a2 += xv.z * wv; a3 += xv.w * wv;
  }
  hnode[(n0 + grp * 4 + 0) * 64 + j] = a0;
  hnode[(n0 + grp * 4 + 1) * 64 + j] = a1;
  hnode[(n0 + grp * 4 + 2) * 64 + j] = a2;
  hnode[(n0 + grp * 4 + 3) * 64 + j] = a3;
}

// ---------------------------------------------------------------------------
// Risk MLP part 2: zero-LDS, 8 lanes per edge, fast tanh/sigmoid, 4 waves/SIMD.
__global__ __launch_bounds__(256, 4) void k_risk_edge(
    const float* __restrict__ hnode, const float* __restrict__ ef, const int* __restrict__ ei,
    const float* __restrict__ w1e, const float* __restrict__ w2, const float* __restrict__ b2_,
    float* __restrict__ rw) {
  int t = threadIdx.x, lane = t & 63, w = t >> 6;
  int g = lane >> 3, s = lane & 7;
  int e = blockIdx.x * 32 + w * 8 + g;
  int row = ei[e];
  const float4* hnode4 = (const float4*)hnode;
  const float4* ef4 = (const float4*)ef;
  const float4* w1e4 = (const float4*)w1e;
  const float4* w24 = (const float4*)w2;
  float ev[32];
#pragma unroll
  for (int i = 0; i < 8; i++) {
    float4 tmp = ef4[e * 8 + i];
    ev[i * 4 + 0] = tmp.x; ev[i * 4 + 1] = tmp.y; ev[i * 4 + 2] = tmp.z; ev[i * 4 + 3] = tmp.w;
  }
  float acc[8];
  {
    float4 ha = hnode4[row * 16 + s * 2];
    float4 hb = hnode4[row * 16 + s * 2 + 1];
    acc[0] = ha.x; acc[1] = ha.y; acc[2] = ha.z; acc[3] = ha.w;
    acc[4] = hb.x; acc[5] = hb.y; acc[6] = hb.z; acc[7] = hb.w;
  }
#pragma unroll
  for (int k = 0; k < 32; k++) {
    float4 wa4 = w1e4[k * 16 + s * 2];
    float4 wb4 = w1e4[k * 16 + s * 2 + 1];
    float ek = ev[k];
    acc[0] += ek * wa4.x; acc[1] += ek * wa4.y; acc[2] += ek * wa4.z; acc[3] += ek * wa4.w;
    acc[4] += ek * wb4.x; acc[5] += ek * wb4.y; acc[6] += ek * wb4.z; acc[7] += ek * wb4.w;
  }
  float4 w2a = w24[s * 2], w2b = w24[s * 2 + 1];
  float vsum = fast_tanh(acc[0]) * w2a.x + fast_tanh(acc[1]) * w2a.y +
               fast_tanh(acc[2]) * w2a.z + fast_tanh(acc[3]) * w2a.w +
               fast_tanh(acc[4]) * w2b.x + fast_tanh(acc[5]) * w2b.y +
               fast_tanh(acc[6]) * w2b.z + fast_tanh(acc[7]) * w2b.w;
  vsum += __shfl_xor(vsum, 1);
  vsum += __shfl_xor(vsum, 2);
  vsum += __shfl_xor(vsum, 4);
  if (s == 0) rw[e] = fast_sigmoid(vsum + b2_[0]);
}

// ---------------------------------------------------------------------------
// Standalone xproj (layer 0 input h): xproj = xh @ wl -> [N,256], fused di/dj.
__global__ __launch_bounds__(256) void k_xproj(
    const float* __restrict__ xh, const float* __restrict__ wl, const float* __restrict__ wa,
    float* __restrict__ xproj, float* __restrict__ di, float* __restrict__ dj) {
  __shared__ float xsT[64][20];
  int t = threadIdx.x, lane = t & 63, w = t >> 6;
  int n0 = blockIdx.x * 16;
  const float4* xh4 = (const float4*)xh;
  {
    int m = t & 15, k4 = t >> 4;
    float4 xv = xh4[(n0 + m) * 16 + k4];
    xsT[k4 * 4 + 0][m] = xv.x;
    xsT[k4 * 4 + 1][m] = xv.y;
    xsT[k4 * 4 + 2][m] = xv.z;
    xsT[k4 * 4 + 3][m] = xv.w;
  }
  __syncthreads();
  float acc[16];
#pragma unroll
  for (int m = 0; m < 16; m++) acc[m] = 0.f;
  for (int k = 0; k < 64; k++) {
    float wv = wl[k * 256 + t];
    float4 xa = *(const float4*)&xsT[k][0];
    float4 xb = *(const float4*)&xsT[k][4];
    float4 xc = *(const float4*)&xsT[k][8];
    float4 xd = *(const float4*)&xsT[k][12];
    acc[0] += xa.x * wv; acc[1] += xa.y * wv; acc[2] += xa.z * wv; acc[3] += xa.w * wv;
    acc[4] += xb.x * wv; acc[5] += xb.y * wv; acc[6] += xb.z * wv; acc[7] += xb.w * wv;
    acc[8] += xc.x * wv; acc[9] += xc.y * wv; acc[10] += xc.z * wv; acc[11] += xc.w * wv;
    acc[12] += xd.x * wv; acc[13] += xd.y * wv; acc[14] += xd.z * wv; acc[15] += xd.w * wv;
  }
  float wai = wa[lane], waj = wa[64 + lane];
#pragma unroll
  for (int m = 0; m < 16; m++) {
    xproj[(n0 + m) * 256 + t] = acc[m];
    float vi = acc[m] * wai;
    float vj = acc[m] * waj;
#pragma unroll
    for (int off = 32; off; off >>= 1) { vi += __shfl_xor(vi, off); vj += __shfl_xor(vj, off); }
    if (lane == 0) { di[(n0 + m) * 4 + w] = vi; dj[(n0 + m) * 4 + w] = vj; }
  }
}

// ---------------------------------------------------------------------------
// alpha + exp fused (softmax shift-invariance; |z| small): p = exp(z), sum partials.
__global__ __launch_bounds__(256) void k_alphaexp(
    const int* __restrict__ ei, const float* __restrict__ di, const float* __restrict__ dj,
    const float* __restrict__ rw, const float* __restrict__ dev3, int layer,
    float* __restrict__ p, float* __restrict__ sumpart, int nb) {
  __shared__ float wred[4][4];
  int t = threadIdx.x, lane = t & 63, w = t >> 6;
  int e = blockIdx.x * 256 + t;  // EE % 256 == 0
  float4 dv = ((const float4*)dev3)[e];
  float dev = (layer == 0) ? dv.x : ((layer == 1) ? dv.y : dv.z);
  int r = ei[e], cl = ei[EE + e];
  float rv = rw[e];
  float4 dir = ((const float4*)di)[r];
  float4 djc = ((const float4*)dj)[cl];
  float z0 = dir.x + djc.x + dev, z1 = dir.y + djc.y + dev;
  float z2 = dir.z + djc.z + dev, z3 = dir.w + djc.w + dev;
  z0 = ((z0 >= 0.f) ? z0 : 0.2f * z0) * rv;
  z1 = ((z1 >= 0.f) ? z1 : 0.2f * z1) * rv;
  z2 = ((z2 >= 0.f) ? z2 : 0.2f * z2) * rv;
  z3 = ((z3 >= 0.f) ? z3 : 0.2f * z3) * rv;
  float4 pv;
  pv.x = __expf(z0); pv.y = __expf(z1); pv.z = __expf(z2); pv.w = __expf(z3);
  ((float4*)p)[e] = pv;
  float sh[4] = {pv.x, pv.y, pv.z, pv.w};
#pragma unroll
  for (int h = 0; h < 4; h++) {
    float v = sh[h];
#pragma unroll
    for (int off = 32; off; off >>= 1) v += __shfl_xor(v, off);
    if (lane == 0) wred[w][h] = v;
  }
  __syncthreads();
  if (t < 4) sumpart[t * nb + blockIdx.x] = wred[0][t] + wred[1][t] + wred[2][t] + wred[3][t];
}

// tiny: inv[h] = 1 / sum(sumpart[h, :])
__global__ __launch_bounds__(256) void k_sinv(
    const float* __restrict__ sumpart, float* __restrict__ inv, int nb) {
  __shared__ float wred[4][4];
  int t = threadIdx.x, lane = t & 63, w = t >> 6;
  float s[4] = {0.f, 0.f, 0.f, 0.f};
  for (int i = t; i < nb; i += 256) {
#pragma unroll
    for (int h = 0; h < 4; h++) s[h] += sumpart[h * nb + i];
  }
#pragma unroll
  for (int h = 0; h < 4; h++) {
    float v = s[h];
#pragma unroll
    for (int off = 32; off; off >>= 1) v += __shfl_xor(v, off);
    if (lane == 0) wred[w][h] = v;
  }
  __syncthreads();
  if (t < 4) inv[t] = 1.f / (wred[0][t] + wred[1][t] + wred[2][t] + wred[3][t]);
}

// ---------------------------------------------------------------------------
// CSR scan + fill (hist fused into edge encoder)
__global__ __launch_bounds__(1024) void k_scan(
    const int* __restrict__ counts, int* __restrict__ rowptr, int* __restrict__ cursor) {
  __shared__ int wsum[16];
  int t = threadIdx.x, lane = t & 63, w = t >> 6;
  const int CH = 20;  // 1024*20 >= NN
  int base_i = t * CH;
  int local = 0;
  for (int i = 0; i < CH; i++) {
    int idx = base_i + i;
    if (idx < NN) local += counts[idx];
  }
  int v = local;
#pragma unroll
  for (int off = 1; off < 64; off <<= 1) {
    int u = __shfl_up(v, off);
    if (lane >= off) v += u;
  }
  if (lane == 63) wsum[w] = v;
  __syncthreads();
  int wbase = 0;
  for (int i = 0; i < w; i++) wbase += wsum[i];
  int run = wbase + v - local;  // exclusive prefix
  for (int i = 0; i < CH; i++) {
    int idx = base_i + i;
    if (idx < NN) {
      rowptr[idx] = run;
      cursor[idx] = run;
      run += counts[idx];
    }
  }
  if (t == 1023) rowptr[NN] = EE;
}
__global__ __launch_bounds__(256) void k_fill(
    const int* __restrict__ ei, int* __restrict__ cursor, int* __restrict__ csr) {
  int e = blockIdx.x * 256 + threadIdx.x;
  if (e < EE) {
    int pos = atomicAdd(&cursor[ei[EE + e]], 1);
    csr[pos] = e;
  }
}

// ---------------------------------------------------------------------------
// Aggregation: wave per node, 2 edges in flight (half-wave slots).
__global__ __launch_bounds__(256) void k_agg(
    const float* __restrict__ p, const float* __restrict__ ef,
    const int* __restrict__ rowptr, const int* __restrict__ csr,
    const float* __restrict__ inv,
    float* __restrict__ sagg, float* __restrict__ tagg) {
  int t = threadIdx.x, lane = t & 63, wv = t >> 6;
  int n = blockIdx.x * 4 + wv;
  int c = lane & 31, slot = lane >> 5;
  float a0 = 0.f, a1 = 0.f, a2 = 0.f, a3 = 0.f;
  float s0 = 0.f, s1 = 0.f, s2 = 0.f, s3 = 0.f;
  int beg = rowptr[n], end = rowptr[n + 1];
  for (int i = beg + slot; i < end; i += 2) {
    int e = csr[i];
    float4 pv = ((const float4*)p)[e];
    float ev = ef[e * 32 + c];
    a0 += pv.x * ev; a1 += pv.y * ev; a2 += pv.z * ev; a3 += pv.w * ev;
    s0 += pv.x; s1 += pv.y; s2 += pv.z; s3 += pv.w;
  }
  a0 += __shfl_xor(a0, 32); a1 += __shfl_xor(a1, 32);
  a2 += __shfl_xor(a2, 32); a3 += __shfl_xor(a3, 32);
  s0 += __shfl_xor(s0, 32); s1 += __shfl_xor(s1, 32);
  s2 += __shfl_xor(s2, 32); s3 += __shfl_xor(s3, 32);
  if (slot == 0) {
    tagg[n * 128 + 0 * 32 + c] = a0 * inv[0];
    tagg[n * 128 + 1 * 32 + c] = a1 * inv[1];
    tagg[n * 128 + 2 * 32 + c] = a2 * inv[2];
    tagg[n * 128 + 3 * 32 + c] = a3 * inv[3];
    if (c < 4) {
      float sv = (c == 0) ? s0 : (c == 1) ? s1 : (c == 2) ? s2 : s3;
      sagg[n * 4 + c] = sv * inv[c];
    }
  }
}

// ---------------------------------------------------------------------------
// Fused node update + next-layer xproj (+di/dj). 16 nodes/block, transposed LDS.
// u = 0.25*(sum_h xproj[n,h]*s[h] + sum_h t[h]@we_h); xh = relu(u@wo+wob);
// if DO_XPROJ: xproj_out = xh @ wl_next (+ di/dj), xh never hits HBM.
template <bool DO_XPROJ>
__global__ __launch_bounds__(256) void k_update_fused(
    const float* __restrict__ xproj, const float* __restrict__ sagg,
    const float* __restrict__ tagg, const float* __restrict__ we,
    const float* __restrict__ wo, const float* __restrict__ wob,
    const float* __restrict__ wl_next, const float* __restrict__ wa_next,
    float* __restrict__ xh_out, float* __restrict__ xproj_out,
    float* __restrict__ di, float* __restrict__ dj) {
  __shared__ float tsT[128][20];
  __shared__ float usT[64][20];
  __shared__ float xhT[64][20];
  __shared__ float ss[16][4];
  int t = threadIdx.x, lane = t & 63, w = t >> 6;
  int n0 = blockIdx.x * 16;
  const float4* tagg4 = (const float4*)tagg;
  for (int i = t; i < 16 * 32; i += 256) {
    int m = i & 15, k4 = i >> 4;
    float4 tv = tagg4[(n0 + m) * 32 + k4];
    tsT[k4 * 4 + 0][m] = tv.x;
    tsT[k4 * 4 + 1][m] = tv.y;
    tsT[k4 * 4 + 2][m] = tv.z;
    tsT[k4 * 4 + 3][m] = tv.w;
  }
  if (t < 64) ss[t >> 2][t & 3] = sagg[n0 * 4 + t];
  __syncthreads();
  int j = lane, grp = w;
  float u0 = 0.f, u1 = 0.f, u2 = 0.f, u3 = 0.f;
#pragma unroll
  for (int h = 0; h < 4; h++) {
    u0 += xproj[(n0 + grp * 4 + 0) * 256 + h * 64 + j] * ss[grp * 4 + 0][h];
    u1 += xproj[(n0 + grp * 4 + 1) * 256 + h * 64 + j] * ss[grp * 4 + 1][h];
    u2 += xproj[(n0 + grp * 4 + 2) * 256 + h * 64 + j] * ss[grp * 4 + 2][h];
    u3 += xproj[(n0 + grp * 4 + 3) * 256 + h * 64 + j] * ss[grp * 4 + 3][h];
  }
  for (int hc = 0; hc < 128; hc++) {
    float wv = we[(hc & 31) * 256 + (hc >> 5) * 64 + j];
    float4 tv = *(const float4*)&tsT[hc][grp * 4];
    u0 += tv.x * wv; u1 += tv.y * wv; u2 += tv.z * wv; u3 += tv.w * wv;
  }
  *(float4*)&usT[j][grp * 4] = make_float4(u0 * 0.25f, u1 * 0.25f, u2 * 0.25f, u3 * 0.25f);
  __syncthreads();
  float ob = wob[j];
  float o0 = ob, o1 = ob, o2 = ob, o3 = ob;
  for (int k = 0; k < 64; k++) {
    float wv = wo[k * 64 + j];
    float4 uv = *(const float4*)&usT[k][grp * 4];
    o0 += uv.x * wv; o1 += uv.y * wv; o2 += uv.z * wv; o3 += uv.w * wv;
  }
  o0 = fmaxf(o0, 0.f); o1 = fmaxf(o1, 0.f); o2 = fmaxf(o2, 0.f); o3 = fmaxf(o3, 0.f);
  if (!DO_XPROJ) {
    xh_out[(n0 + grp * 4 + 0) * 64 + j] = o0;
    xh_out[(n0 + grp * 4 + 1) * 64 + j] = o1;
    xh_out[(n0 + grp * 4 + 2) * 64 + j] = o2;
    xh_out[(n0 + grp * 4 + 3) * 64 + j] = o3;
    return;
  }
  xhT[j][grp * 4 + 0] = o0;
  xhT[j][grp * 4 + 1] = o1;
  xhT[j][grp * 4 + 2] = o2;
  xhT[j][grp * 4 + 3] = o3;
  __syncthreads();
  float acc[16];
#pragma unroll
  for (int m = 0; m < 16; m++) acc[m] = 0.f;
  for (int k = 0; k < 64; k++) {
    float wv = wl_next[k * 256 + t];
    float4 xa = *(const float4*)&xhT[k][0];
    float4 xb = *(const float4*)&xhT[k][4];
    float4 xc = *(const float4*)&xhT[k][8];
    float4 xd = *(const float4*)&xhT[k][12];
    acc[0] += xa.x * wv; acc[1] += xa.y * wv; acc[2] += xa.z * wv; acc[3] += xa.w * wv;
    acc[4] += xb.x * wv; acc[5] += xb.y * wv; acc[6] += xb.z * wv; acc[7] += xb.w * wv;
    acc[8] += xc.x * wv; acc[9] += xc.y * wv; acc[10] += xc.z * wv; acc[11] += xc.w * wv;
    acc[12] += xd.x * wv; acc[13] += xd.y * wv; acc[14] += xd.z * wv; acc[15] += xd.w * wv;
  }
  float wai = wa_next[lane], waj = wa_next[64 + lane];
#pragma unroll
  for (int m = 0; m < 16; m++) {
    xproj_out[(n0 + m) * 256 + t] = acc[m];
    float vi = acc[m] * wai;
    float vj = acc[m] * waj;
#pragma unroll
    for (int off = 32; off; off >>= 1) { vi += __shfl_xor(vi, off); vj += __shfl_xor(vj, off); }
    if (lane == 0) { di[(n0 + m) * 4 + w] = vi; dj[(n0 + m) * 4 + w] = vj; }
  }
}

// ---------------------------------------------------------------------------
// Output layer: Linear(64,128)+ReLU+Linear(128,256)+LayerNorm(256). 8 nodes/block.
#define OPN 8
__global__ __launch_bounds__(256) void k_out(
    const float* __restrict__ xh, const float* __restrict__ w1, const float* __restrict__ b1,
    const float* __restrict__ w2, const float* __restrict__ b2,
    const float* __restrict__ g, const float* __restrict__ beta,
    float* __restrict__ out) {
  __shared__ float xsT[64][12];
  __shared__ float hsT[128][12];
  __shared__ float wp[4], wq[4];
  int t = threadIdx.x, lane = t & 63, w = t >> 6;
  int n0 = blockIdx.x * OPN;
  const float4* xh4 = (const float4*)xh;
  if (t < 128) {
    int m = t >> 4, k4 = t & 15;
    float4 xv = xh4[(n0 + m) * 16 + k4];
    xsT[k4 * 4 + 0][m] = xv.x;
    xsT[k4 * 4 + 1][m] = xv.y;
    xsT[k4 * 4 + 2][m] = xv.z;
    xsT[k4 * 4 + 3][m] = xv.w;
  }
  __syncthreads();
  for (int i = t; i < OPN * 128; i += 256) {
    int m = i >> 7, jj = i & 127;
    float a = b1[jj];
#pragma unroll
    for (int k = 0; k < 64; k++) a += xsT[k][m] * w1[k * 128 + jj];
    hsT[jj][m] = fmaxf(a, 0.f);
  }
  __syncthreads();
  float o[OPN];
  float bb = b2[t];
#pragma unroll
  for (int m = 0; m < OPN; m++) o[m] = bb;
  for (int k = 0; k < 128; k++) {
    float wv = w2[k * 256 + t];
    float4 ha = *(const float4*)&hsT[k][0];
    float4 hb = *(const float4*)&hsT[k][4];
    o[0] += ha.x * wv; o[1] += ha.y * wv; o[2] += ha.z * wv; o[3] += ha.w * wv;
    o[4] += hb.x * wv; o[5] += hb.y * wv; o[6] += hb.z * wv; o[7] += hb.w * wv;
  }
  float gv = g[t], bv = beta[t];
#pragma unroll
  for (int m = 0; m < OPN; m++) {
    float v = o[m], vv = o[m] * o[m];
#pragma unroll
    for (int off = 32; off; off >>= 1) { v += __shfl_xor(v, off); vv += __shfl_xor(vv, off); }
    if (lane == 0) { wp[w] = v; wq[w] = vv; }
    __syncthreads();
    float mean = (wp[0] + wp[1] + wp[2] + wp[3]) * (1.f / 256.f);
    float ex2 = (wq[0] + wq[1] + wq[2] + wq[3]) * (1.f / 256.f);
    float var = ex2 - mean * mean;
    __syncthreads();
    out[(n0 + m) * 256 + t] = (o[m] - mean) * rsqrtf(var + 1e-5f) * gv + bv;
  }
}

// ---------------------------------------------------------------------------
extern "C" void kernel_launch(void* const* d_in, const int* in_sizes, int n_in,
                              void* d_out, int out_size, void* d_ws, size_t ws_size,
                              hipStream_t stream) {
  const float* x         = (const float*)d_in[0];
  const float* edge_attr = (const float*)d_in[1];
  const int*   ei        = (const int*)d_in[2];
  const float* ne_w1 = (const float*)d_in[3];
  const float* ne_b1 = (const float*)d_in[4];
  const float* ne_w2 = (const float*)d_in[5];
  const float* ne_b2 = (const float*)d_in[6];
  const float* ne_g  = (const float*)d_in[7];
  const float* ne_be = (const float*)d_in[8];
  const float* ee_w1 = (const float*)d_in[9];
  const float* ee_b1 = (const float*)d_in[10];
  const float* ee_w2 = (const float*)d_in[11];
  const float* ee_b2 = (const float*)d_in[12];
  const float* ee_g  = (const float*)d_in[13];
  const float* ee_be = (const float*)d_in[14];
  const float* ra_w1 = (const float*)d_in[15];
  const float* ra_b1 = (const float*)d_in[16];
  const float* ra_w2 = (const float*)d_in[17];
  const float* ra_b2 = (const float*)d_in[18];
  const float* gat_wl  = (const float*)d_in[19];
  const float* gat_wa  = (const float*)d_in[20];
  const float* gat_we  = (const float*)d_in[21];
  const float* gat_wo  = (const float*)d_in[22];
  const float* gat_wob = (const float*)d_in[23];
  const float* ow_1 = (const float*)d_in[24];
  const float* ob_1 = (const float*)d_in[25];
  const float* ow_2 = (const float*)d_in[26];
  const float* ob_2 = (const float*)d_in[27];
  const float* o_g  = (const float*)d_in[28];
  const float* o_be = (const float*)d_in[29];
  float* out = (float*)d_out;

  char* wsb = (char*)d_ws;
  size_t off = 0;
  auto af = [&](size_t elems) -> float* { float* p = (float*)(wsb + off); off += elems * sizeof(float); return p; };
  auto ai = [&](size_t elems) -> int*   { int*   p = (int*)(wsb + off);   off += elems * sizeof(int);   return p; };

  const int nb = EE / 256;  // 1250

  float* h      = af((size_t)NN * 64);
  float* xh2    = af((size_t)NN * 64);
  float* ef     = af((size_t)EE * 32);
  float* rw     = af((size_t)EE);
  float* dev3   = af((size_t)EE * 4);
  float* xprojA = af((size_t)NN * 256);
  float* xprojB = af((size_t)NN * 256);   // aliased as hnode before layer 1
  float* di     = af((size_t)NN * 4);
  float* dj     = af((size_t)NN * 4);
  float* p      = af((size_t)EE * 4);
  float* sagg   = af((size_t)NN * 4);
  float* tagg   = af((size_t)NN * 128);
  float* sumpart= af((size_t)4 * nb);
  float* invs   = af(4);
  int* counts = ai(NN);
  int* rowptr = ai(NN + 1);
  int* cursor = ai(NN);
  int* csr    = ai(EE);
  float* hnode = xprojB;  // consumed by k_risk_edge before xprojB's first use
  (void)ws_size; (void)n_in; (void)in_sizes; (void)out_size;

  hipMemsetAsync(counts, 0, NN * sizeof(int), stream);
  k_node_enc<<<(NN + 255) / 256, 256, 0, stream>>>(x, ne_w1, ne_b1, ne_w2, ne_b2, ne_g, ne_be, h);
  k_edge_enc<<<EE / 256, 256, 0, stream>>>(edge_attr, ee_w1, ee_b1, ee_w2, ee_b2, ee_g, ee_be,
                                           gat_wa, ei, ef, dev3, counts);
  k_risk_node<<<NN / 16, 256, 0, stream>>>(h, ra_w1, ra_b1, hnode);
  k_risk_edge<<<EE / 32, 256, 0, stream>>>(hnode, ef, ei, ra_w1 + 64 * 64, ra_w2, ra_b2, rw);
  k_scan<<<1, 1024, 0, stream>>>(counts, rowptr, cursor);
  k_fill<<<EE / 256, 256, 0, stream>>>(ei, cursor, csr);

  // layer-0 projection from h
  k_xproj<<<NN / 16, 256, 0, stream>>>(h, gat_wl, gat_wa, xprojA, di, dj);

  float* xp_cur = xprojA;
  float* xp_nxt = xprojB;
  for (int l = 0; l < 3; l++) {
    const float* we  = gat_we + (size_t)l * 32 * 256;
    const float* wo  = gat_wo + (size_t)l * 64 * 64;
    const float* wob = gat_wob + (size_t)l * 64;

    k_alphaexp<<<nb, 256, 0, stream>>>(ei, di, dj, rw, dev3, l, p, sumpart, nb);
    k_sinv<<<1, 256, 0, stream>>>(sumpart, invs, nb);
    k_agg<<<NN / 4, 256, 0, stream>>>(p, ef, rowptr, csr, invs, sagg, tagg);
    if (l < 2) {
      const float* wl_n = gat_wl + (size_t)(l + 1) * 64 * 256;
      const float* wa_n = gat_wa + (size_t)(l + 1) * 160;
      k_update_fused<true><<<NN / 16, 256, 0, stream>>>(
          xp_cur, sagg, tagg, we, wo, wob, wl_n, wa_n, nullptr, xp_nxt, di, dj);
      float* tmp = xp_cur; xp_cur = xp_nxt; xp_nxt = tmp;
    } else {
      k_update_fused<false><<<NN / 16, 256, 0, stream>>>(
          xp_cur, sagg, tagg, we, wo, wob, nullptr, nullptr, xh2, nullptr, nullptr, nullptr);
    }
  }

  k_out<<<NN / OPN, 256, 0, stream>>>(xh2, ow_1, ob_1, ow_2, ob_2, o_g, o_be, out);
}